// Round 1
// baseline (3376.634 us; speedup 1.0000x reference)
//
#include <hip/hip_runtime.h>
#include <cstddef>
#include <cstdint>

// ---------------- problem constants (match reference) ----------------
static constexpr int NP = 60000, NA = 30000;
static constexpr int EC = 300000, EW = 150000, EB = 150000;
static constexpr int IN_F = 1024, HID = 512, H = 4, D = 128, NCLS = 153;
static constexpr int MPAD_P = 60160;  // 235 * 256
static constexpr int MPAD_A = 30208;  // 118 * 256

typedef __attribute__((ext_vector_type(8))) short short8;
typedef __attribute__((ext_vector_type(4))) float float4v;

// ---------------- bf16 helpers (RNE) ----------------
__device__ __forceinline__ unsigned short f2bf(float f) {
    unsigned int u = __float_as_uint(f);
    unsigned int r = u + 0x7FFFu + ((u >> 16) & 1u);
    return (unsigned short)(r >> 16);
}
__device__ __forceinline__ float bf2f(unsigned short h) {
    return __uint_as_float(((unsigned int)h) << 16);
}

// async global->LDS, 16B per lane; lds base must be wave-uniform
__device__ __forceinline__ void gll16(const unsigned short* g, unsigned short* l) {
    __builtin_amdgcn_global_load_lds(
        (const __attribute__((address_space(1))) unsigned int*)g,
        (__attribute__((address_space(3))) unsigned int*)l, 16, 0, 0);
}

// ---------------- CSR build ----------------
__global__ void hist_kernel(const int* __restrict__ dst, int E, int* __restrict__ counts) {
    int e = blockIdx.x * 256 + threadIdx.x;
    if (e < E) atomicAdd(&counts[dst[e]], 1);
}

__global__ void exscan_kernel(const int* __restrict__ in, int* __restrict__ out, int n) {
    __shared__ int wsum[4];
    int t = threadIdx.x;
    int lane = t & 63, w = t >> 6;
    int carry = 0;
    const int CH = 256 * 8;
    for (int base = 0; base < n; base += CH) {
        int v[8], run[8];
        int i0 = base + t * 8;
        int tsum = 0;
#pragma unroll
        for (int j = 0; j < 8; ++j) {
            int i = i0 + j;
            v[j] = (i < n) ? in[i] : 0;
            tsum += v[j];
            run[j] = tsum;
        }
        int x = tsum;
#pragma unroll
        for (int off = 1; off < 64; off <<= 1) {
            int y = __shfl_up(x, off);
            if (lane >= off) x += y;
        }
        if (lane == 63) wsum[w] = x;
        __syncthreads();
        int wpre = 0;
        for (int ww = 0; ww < w; ++ww) wpre += wsum[ww];
        int chunktot = wsum[0] + wsum[1] + wsum[2] + wsum[3];
        int pre = carry + wpre + (x - tsum);
#pragma unroll
        for (int j = 0; j < 8; ++j) {
            int i = i0 + j;
            if (i < n) out[i] = pre + run[j] - v[j];
        }
        carry += chunktot;
        __syncthreads();
    }
    if (t == 0) out[n] = carry;
}

__global__ void fill_kernel(const int* __restrict__ src, const int* __restrict__ dst, int E,
                            int* __restrict__ cursor, int* __restrict__ col) {
    int e = blockIdx.x * 256 + threadIdx.x;
    if (e < E) {
        int pos = atomicAdd(&cursor[dst[e]], 1);
        col[pos] = src[e];
    }
}

// ---------------- split-bf16 prep ----------------
__global__ void decomp4_kernel(const float4* __restrict__ x, ushort4* __restrict__ hi,
                               ushort4* __restrict__ lo, int M, int K, int Mpad) {
    size_t i4 = (size_t)blockIdx.x * 256 + threadIdx.x;
    size_t tot = ((size_t)Mpad * K) >> 2;
    if (i4 >= tot) return;
    size_t row = (i4 * 4) / (size_t)K;
    float4 v = make_float4(0.f, 0.f, 0.f, 0.f);
    if (row < (size_t)M) v = x[i4];
    ushort4 h, l;
    h.x = f2bf(v.x); h.y = f2bf(v.y); h.z = f2bf(v.z); h.w = f2bf(v.w);
    l.x = f2bf(v.x - bf2f(h.x)); l.y = f2bf(v.y - bf2f(h.y));
    l.z = f2bf(v.z - bf2f(h.z)); l.w = f2bf(v.w - bf2f(h.w));
    hi[i4] = h; lo[i4] = l;
}

// B (K x N, ld=N) -> BT hi/lo (Npad x K), zero pad rows
__global__ void btprep_kernel(const float* __restrict__ W, unsigned short* __restrict__ hi,
                              unsigned short* __restrict__ lo, int K, int N, int Npad) {
    int i = blockIdx.x * 256 + threadIdx.x;
    if (i >= Npad * K) return;
    int n = i / K, k = i - n * K;
    float v = (n < N) ? W[(size_t)k * N + n] : 0.f;
    unsigned short h = f2bf(v);
    hi[i] = h;
    lo[i] = f2bf(v - bf2f(h));
}

// ---------------- MFMA split-bf16 GEMM, K-concatenated single pass ----------------
// C = (Ahi+Alo)[MxK] @ (Bhi+Blo)^T via per-32-chunk segment sequence
//   seg0: Ahi*Bhi, seg1: Alo*Bhi, seg2: Ahi*Blo  (same accumulation order as 3-pass)
// Tile: BM=BN=256, BK=32, 8 waves (2Mx4N), per-wave 128x64 (8x4 frags).
// LDS: 4-slot ring x (A 256x32 + B 256x32) bf16 = 4 x 32KB = 128KB (dynamic).
// Pipeline: prefetch 3 tiles ahead via global_load_lds; counted s_waitcnt vmcnt(12)
// (never 0 in main loop); raw s_barrier; setprio(1) around MFMA cluster.
// LDS swizzle: 16B chunk' = chunk ^ ((row>>1)&3), applied on global source (write
// side, since global_load_lds dest is linear) AND on ds_read address (read side).
__global__ __launch_bounds__(512, 2) void gemm_ring(
    const unsigned short* __restrict__ Ahi, const unsigned short* __restrict__ Alo,
    const unsigned short* __restrict__ Bhi, const unsigned short* __restrict__ Blo,
    const float* __restrict__ bias, float* __restrict__ C,
    int M, int K, int Nstore, int ldc) {
    extern __shared__ unsigned short lds[];  // 4 * 16384 shorts
    const int tid = threadIdx.x;
    const int lane = tid & 63;
    const int w = tid >> 6;           // 8 waves
    const int wr = w >> 2, wc = w & 3;
    const int bm = blockIdx.y * 256, bn = blockIdx.x * 256;

    // ---- staging source (pre-swizzled 16B chunk): row = w*16 + (lane>>2) (+128)
    // f(row) = (row>>1)&3 = (lane>>3)&3 here; source chunk = (lane&3) ^ f
    const int st_row = w * 16 + (lane >> 2);
    const int st_sc = (((lane & 3) ^ ((lane >> 3) & 3)) << 3);  // shorts
    const size_t aoff0 = (size_t)(bm + st_row) * K + st_sc;
    const size_t aoff1 = aoff0 + (size_t)128 * K;
    const size_t boff0 = (size_t)(bn + st_row) * K + st_sc;
    const size_t boff1 = boff0 + (size_t)128 * K;
    const int ldsA = w * 512;          // wave-uniform dest (shorts), issue1 = +4096
    const int ldsB = 8192 + w * 512;

    // ---- fragment read addressing (swizzled): f(row)=(lane>>1)&3 (row-low-bits only)
    const int arow = wr * 128 + (lane & 15);
    const int brow = wc * 64 + (lane & 15);
    const int rq = ((((lane >> 4) & 3) ^ ((lane >> 1) & 3)) << 3);
    const int aRead = arow * 32 + rq;
    const int bRead = 8192 + brow * 32 + rq;

    float4v acc[8][4];
    float4v zf = {0.f, 0.f, 0.f, 0.f};
#pragma unroll
    for (int i = 0; i < 8; ++i)
#pragma unroll
        for (int j = 0; j < 4; ++j) acc[i][j] = zf;

    auto STAGE = [&](unsigned rr, const unsigned short* As, const unsigned short* Bs, int kc) {
        unsigned short* sb = &lds[rr * 16384u];
        gll16(As + aoff0 + kc, sb + ldsA);
        gll16(As + aoff1 + kc, sb + ldsA + 4096);
        gll16(Bs + boff0 + kc, sb + ldsB);
        gll16(Bs + boff1 + kc, sb + ldsB + 4096);
    };
    auto COMPUTE = [&](unsigned rr) {
        const unsigned short* sb = &lds[rr * 16384u];
        short8 fa[8], fb[4];
#pragma unroll
        for (int i = 0; i < 8; ++i) fa[i] = *(const short8*)&sb[aRead + i * 512];
#pragma unroll
        for (int j = 0; j < 4; ++j) fb[j] = *(const short8*)&sb[bRead + j * 512];
        __builtin_amdgcn_s_setprio(1);
#pragma unroll
        for (int i = 0; i < 8; ++i)
#pragma unroll
            for (int j = 0; j < 4; ++j)
                acc[i][j] = __builtin_amdgcn_mfma_f32_16x16x32_bf16(fa[i], fb[j], acc[i][j], 0, 0, 0);
        __builtin_amdgcn_s_setprio(0);
    };

#define WAITV(n) asm volatile("s_waitcnt vmcnt(" #n ")" ::: "memory")
#define BARF()                                 \
    do {                                       \
        asm volatile("" ::: "memory");         \
        __builtin_amdgcn_s_barrier();          \
        asm volatile("" ::: "memory");         \
    } while (0)

    // prologue: stage chunk 0, all 3 segments, into ring slots 0,1,2
    STAGE(0, Ahi, Bhi, 0);
    STAGE(1, Alo, Bhi, 0);
    STAGE(2, Ahi, Blo, 0);
    unsigned rg = 0;
    const int nK = K >> 5;  // 32-wide k-chunks
#pragma unroll 1
    for (int t3 = 0; t3 < nK - 1; ++t3) {
        const int kn = (t3 + 1) << 5;
        // seg0: prefetch next chunk's seg0 (3 tiles ahead), consume ring rg
        STAGE((rg + 3) & 3, Ahi, Bhi, kn);
        WAITV(12);
        BARF();
        COMPUTE(rg);
        BARF();
        rg = (rg + 1) & 3;
        // seg1
        STAGE((rg + 3) & 3, Alo, Bhi, kn);
        WAITV(12);
        BARF();
        COMPUTE(rg);
        BARF();
        rg = (rg + 1) & 3;
        // seg2
        STAGE((rg + 3) & 3, Ahi, Blo, kn);
        WAITV(12);
        BARF();
        COMPUTE(rg);
        BARF();
        rg = (rg + 1) & 3;
    }
    // epilogue chunk (no prefetch): drain 8 -> 4 -> 0
    WAITV(8);
    BARF();
    COMPUTE(rg);
    BARF();
    rg = (rg + 1) & 3;
    WAITV(4);
    BARF();
    COMPUTE(rg);
    BARF();
    rg = (rg + 1) & 3;
    WAITV(0);
    BARF();
    COMPUTE(rg);
#undef WAITV
#undef BARF

    // C/D layout: col = lane&15, row = (lane>>4)*4 + reg
    const int col0 = bn + wc * 64 + (lane & 15);
    const int row0 = bm + wr * 128 + ((lane >> 4) << 2);
#pragma unroll
    for (int i = 0; i < 8; ++i) {
#pragma unroll
        for (int j = 0; j < 4; ++j) {
            int col = col0 + j * 16;
            if (col >= Nstore) continue;
            float badd = bias ? bias[col] : 0.f;
            int rowb = row0 + i * 16;
#pragma unroll
            for (int k = 0; k < 4; ++k) {
                int row = rowb + k;
                if (row < M) C[(size_t)row * ldc + col] = acc[i][j][k] + badd;
            }
        }
    }
}

// ---------------- el / er from z (one wave per row) ----------------
__global__ __launch_bounds__(256) void eler_kernel(
    const float* __restrict__ z, const float* __restrict__ al, const float* __restrict__ ar,
    float* __restrict__ el, float* __restrict__ er, int M) {
    int row = blockIdx.x * 4 + (threadIdx.x >> 6);
    int lane = threadIdx.x & 63;
    if (row >= M) return;
    const float4* zr = (const float4*)(z + (size_t)row * 512 + lane * 8);
    float4 z0 = zr[0], z1 = zr[1];
    const float4* alp = (const float4*)(al + lane * 8);
    float4 a0 = alp[0], a1 = alp[1];
    float s = z0.x * a0.x + z0.y * a0.y + z0.z * a0.z + z0.w * a0.w
            + z1.x * a1.x + z1.y * a1.y + z1.z * a1.z + z1.w * a1.w;
    s += __shfl_xor(s, 8); s += __shfl_xor(s, 4); s += __shfl_xor(s, 2); s += __shfl_xor(s, 1);
    int h = lane >> 4;
    if ((lane & 15) == 0) el[(size_t)row * 4 + h] = s;
    if (er) {
        const float4* arp = (const float4*)(ar + lane * 8);
        float4 b0 = arp[0], b1 = arp[1];
        float t = z0.x * b0.x + z0.y * b0.y + z0.z * b0.z + z0.w * b0.w
                + z1.x * b1.x + z1.y * b1.y + z1.z * b1.z + z1.w * b1.w;
        t += __shfl_xor(t, 8); t += __shfl_xor(t, 4); t += __shfl_xor(t, 2); t += __shfl_xor(t, 1);
        if ((lane & 15) == 0) er[(size_t)row * 4 + h] = t;
    }
}

// ---------------- fold: v[k,h] = sum_d W[k, h*128+d] * ar[h,d] ----------------
__global__ void fold_kernel(const float* __restrict__ W, const float* __restrict__ ar,
                            float* __restrict__ v, int K) {
    int i = blockIdx.x * 256 + threadIdx.x;
    if (i >= K * 4) return;
    int k = i >> 2, h = i & 3;
    const float* wr = W + (size_t)k * 512 + h * 128;
    const float* a = ar + h * 128;
    float s = 0.f;
#pragma unroll 4
    for (int d = 0; d < 128; ++d) s += wr[d] * a[d];
    v[i] = s;
}

// ---------------- skinny: er[M,4] = h[M,K] @ v[K,4] ----------------
__global__ __launch_bounds__(256) void skinny_kernel(
    const float* __restrict__ h, const float* __restrict__ v,
    float* __restrict__ er, int M, int K) {
    __shared__ float vs[4096];
    for (int i = threadIdx.x; i < K * 4; i += 256) vs[i] = v[i];
    __syncthreads();
    int row = blockIdx.x * 4 + (threadIdx.x >> 6);
    int lane = threadIdx.x & 63;
    if (row >= M) return;
    const float* hr = h + (size_t)row * K;
    float a0 = 0, a1 = 0, a2 = 0, a3 = 0;
    for (int k = lane; k < K; k += 64) {
        float x = hr[k];
        float4 vv = *(const float4*)&vs[k * 4];
        a0 += x * vv.x; a1 += x * vv.y; a2 += x * vv.z; a3 += x * vv.w;
    }
#pragma unroll
    for (int off = 32; off; off >>= 1) {
        a0 += __shfl_xor(a0, off); a1 += __shfl_xor(a1, off);
        a2 += __shfl_xor(a2, off); a3 += __shfl_xor(a3, off);
    }
    if (lane == 0) *(float4*)&er[(size_t)row * 4] = make_float4(a0, a1, a2, a3);
}

// ---------------- fused softmax-stats + aggregation (+relu +decomp) ----------------
__global__ __launch_bounds__(256) void agg_fused(
    const int* __restrict__ rp1, const int* __restrict__ col1, const float* __restrict__ z1,
    const float* __restrict__ el1, const float* __restrict__ er1,
    const int* __restrict__ rp2, const int* __restrict__ col2, const float* __restrict__ z2,
    const float* __restrict__ el2, const float* __restrict__ er2,
    float* __restrict__ out, unsigned short* __restrict__ hi, unsigned short* __restrict__ lo,
    int N, int do_relu) {
    int j = blockIdx.x * 4 + (threadIdx.x >> 6);
    int lane = threadIdx.x & 63;
    if (j >= N) return;
    int h = lane >> 4;
    float4 acc0 = make_float4(0, 0, 0, 0), acc1 = make_float4(0, 0, 0, 0);

    // ---- type 1 ----
    {
        int e0 = rp1[j], e1 = rp1[j + 1];
        float erh = er1[(size_t)j * 4 + h];
        float m = -INFINITY, s = 0.f;
        for (int e = e0; e < e1; ++e) {
            float x = el1[(size_t)col1[e] * 4 + h] + erh;
            x = (x >= 0.f) ? x : 0.2f * x;
            float mn = fmaxf(m, x);
            s = s * expf(m - mn) + expf(x - mn);
            m = mn;
        }
        float inv = 1.0f / (s + 1e-9f);
        for (int e = e0; e < e1; ++e) {
            int src = col1[e];
            float x = el1[(size_t)src * 4 + h] + erh;
            x = (x >= 0.f) ? x : 0.2f * x;
            float wgt = expf(x - m) * inv;
            const float4* zr = (const float4*)(z1 + (size_t)src * 512 + lane * 8);
            float4 za = zr[0], zb = zr[1];
            acc0.x += wgt * za.x; acc0.y += wgt * za.y; acc0.z += wgt * za.z; acc0.w += wgt * za.w;
            acc1.x += wgt * zb.x; acc1.y += wgt * zb.y; acc1.z += wgt * zb.z; acc1.w += wgt * zb.w;
        }
    }
    // ---- type 2 (optional) ----
    if (rp2) {
        int e0 = rp2[j], e1 = rp2[j + 1];
        float erh = er2[(size_t)j * 4 + h];
        float m = -INFINITY, s = 0.f;
        for (int e = e0; e < e1; ++e) {
            float x = el2[(size_t)col2[e] * 4 + h] + erh;
            x = (x >= 0.f) ? x : 0.2f * x;
            float mn = fmaxf(m, x);
            s = s * expf(m - mn) + expf(x - mn);
            m = mn;
        }
        float inv = 1.0f / (s + 1e-9f);
        for (int e = e0; e < e1; ++e) {
            int src = col2[e];
            float x = el2[(size_t)src * 4 + h] + erh;
            x = (x >= 0.f) ? x : 0.2f * x;
            float wgt = expf(x - m) * inv;
            const float4* zr = (const float4*)(z2 + (size_t)src * 512 + lane * 8);
            float4 za = zr[0], zb = zr[1];
            acc0.x += wgt * za.x; acc0.y += wgt * za.y; acc0.z += wgt * za.z; acc0.w += wgt * za.w;
            acc1.x += wgt * zb.x; acc1.y += wgt * zb.y; acc1.z += wgt * zb.z; acc1.w += wgt * zb.w;
        }
    }
    if (do_relu) {
        acc0.x = fmaxf(acc0.x, 0.f); acc0.y = fmaxf(acc0.y, 0.f);
        acc0.z = fmaxf(acc0.z, 0.f); acc0.w = fmaxf(acc0.w, 0.f);
        acc1.x = fmaxf(acc1.x, 0.f); acc1.y = fmaxf(acc1.y, 0.f);
        acc1.z = fmaxf(acc1.z, 0.f); acc1.w = fmaxf(acc1.w, 0.f);
    }
    float* op = out + (size_t)j * 512 + lane * 8;
    *(float4*)op = acc0;
    *(float4*)(op + 4) = acc1;
    if (hi) {
        size_t base = (size_t)j * 512 + lane * 8;
        ushort4 h0, h1, l0, l1;
        h0.x = f2bf(acc0.x); h0.y = f2bf(acc0.y); h0.z = f2bf(acc0.z); h0.w = f2bf(acc0.w);
        h1.x = f2bf(acc1.x); h1.y = f2bf(acc1.y); h1.z = f2bf(acc1.z); h1.w = f2bf(acc1.w);
        l0.x = f2bf(acc0.x - bf2f(h0.x)); l0.y = f2bf(acc0.y - bf2f(h0.y));
        l0.z = f2bf(acc0.z - bf2f(h0.z)); l0.w = f2bf(acc0.w - bf2f(h0.w));
        l1.x = f2bf(acc1.x - bf2f(h1.x)); l1.y = f2bf(acc1.y - bf2f(h1.y));
        l1.z = f2bf(acc1.z - bf2f(h1.z)); l1.w = f2bf(acc1.w - bf2f(h1.w));
        *(ushort4*)(hi + base) = h0;
        *(ushort4*)(hi + base + 4) = h1;
        *(ushort4*)(lo + base) = l0;
        *(ushort4*)(lo + base + 4) = l1;
    }
}

// ---------------- launcher ----------------
extern "C" void kernel_launch(void* const* d_in, const int* in_sizes, int n_in,
                              void* d_out, int out_size, void* d_ws, size_t ws_size,
                              hipStream_t stream) {
    const float* x_paper = (const float*)d_in[0];
    const float* x_author = (const float*)d_in[1];
    const int* cites_src = (const int*)d_in[2];
    const int* cites_dst = (const int*)d_in[3];
    const int* writes_src = (const int*)d_in[4];
    const int* writes_dst = (const int*)d_in[5];
    const int* wb_src = (const int*)d_in[6];
    const int* wb_dst = (const int*)d_in[7];
    const float* W0 = (const float*)d_in[8];
    const float* al0 = (const float*)d_in[9];
    const float* ar0 = (const float*)d_in[10];
    const float* W1 = (const float*)d_in[11];
    const float* al1 = (const float*)d_in[12];
    const float* ar1 = (const float*)d_in[13];
    const float* W2 = (const float*)d_in[14];
    const float* al2 = (const float*)d_in[15];
    const float* ar2 = (const float*)d_in[16];
    const float* linW = (const float*)d_in[17];
    const float* linb = (const float*)d_in[18];
    float* out = (float*)d_out;

    // allow 128KB dynamic LDS for the ring GEMM (host-side, capture-safe)
    (void)hipFuncSetAttribute((const void*)gemm_ring,
                              hipFuncAttributeMaxDynamicSharedMemorySize, 131072);

    char* p = (char*)d_ws;
    auto alloc = [&](size_t n) { char* r = p; p += (n + 255) & ~(size_t)255; return r; };

    float* hpA = (float*)alloc((size_t)NP * 512 * 4);
    float* hpB = (float*)alloc((size_t)NP * 512 * 4);
    float* haA = (float*)alloc((size_t)NA * 512 * 4);
    float* haB = (float*)alloc((size_t)NA * 512 * 4);
    float* zbuf = (float*)alloc((size_t)NP * 512 * 4);   // paper-source z
    float* elA = (float*)alloc((size_t)NP * 16);
    float* erA = (float*)alloc((size_t)NP * 16);
    float* elB = (float*)alloc((size_t)NP * 16);
    float* erB = (float*)alloc((size_t)NP * 16);
    float* vfold = (float*)alloc(4096 * 4);
    int* rp_c = (int*)alloc((NP + 1) * 4);
    int* col_c = (int*)alloc((size_t)EC * 4);
    int* rp_w = (int*)alloc((NP + 1) * 4);
    int* col_w = (int*)alloc((size_t)EW * 4);
    int* rp_b = (int*)alloc((NA + 1) * 4);
    int* col_b = (int*)alloc((size_t)EB * 4);
    int* cursor = (int*)alloc((NP + 1) * 4);
    int* counts = (int*)alloc((size_t)NP * 4);

    unsigned short* AhiP = (unsigned short*)alloc((size_t)MPAD_P * 1024 * 2);
    unsigned short* AloP = (unsigned short*)alloc((size_t)MPAD_P * 1024 * 2);
    unsigned short* AhiA = (unsigned short*)alloc((size_t)MPAD_A * 1024 * 2);
    unsigned short* AloA = (unsigned short*)alloc((size_t)MPAD_A * 1024 * 2);
    const int Ks[3] = {IN_F, HID, HID};
    unsigned short *bthi[3][3], *btlo[3][3];
    for (int l = 0; l < 3; ++l)
        for (int t = 0; t < 3; ++t) {
            bthi[l][t] = (unsigned short*)alloc((size_t)512 * Ks[l] * 2);
            btlo[l][t] = (unsigned short*)alloc((size_t)512 * Ks[l] * 2);
        }
    unsigned short* btLhi = (unsigned short*)alloc((size_t)256 * 512 * 2);
    unsigned short* btLlo = (unsigned short*)alloc((size_t)256 * 512 * 2);
    (void)ws_size;

    // ---- CSR build ----
    struct EdgeT { const int* src; const int* dst; int E; int n; int* rp; int* col; };
    EdgeT ets[3] = {
        {cites_src, cites_dst, EC, NP, rp_c, col_c},
        {writes_src, writes_dst, EW, NP, rp_w, col_w},
        {wb_src, wb_dst, EB, NA, rp_b, col_b},
    };
    for (int t = 0; t < 3; ++t) {
        hipMemsetAsync(counts, 0, (size_t)ets[t].n * 4, stream);
        hist_kernel<<<(ets[t].E + 255) / 256, 256, 0, stream>>>(ets[t].dst, ets[t].E, counts);
        exscan_kernel<<<1, 256, 0, stream>>>(counts, ets[t].rp, ets[t].n);
        hipMemcpyAsync(cursor, ets[t].rp, (size_t)ets[t].n * 4, hipMemcpyDeviceToDevice, stream);
        fill_kernel<<<(ets[t].E + 255) / 256, 256, 0, stream>>>(ets[t].src, ets[t].dst, ets[t].E, cursor, ets[t].col);
    }

    const float* Wl[3] = {W0, W1, W2};
    const float* alL[3] = {al0, al1, al2};
    const float* arL[3] = {ar0, ar1, ar2};

    // ---- weight transpose + hi/lo decomposition ----
    for (int l = 0; l < 3; ++l) {
        int K = Ks[l];
        for (int t = 0; t < 3; ++t)
            btprep_kernel<<<(512 * K + 255) / 256, 256, 0, stream>>>(
                Wl[l] + (size_t)t * K * 512, bthi[l][t], btlo[l][t], K, 512, 512);
    }
    btprep_kernel<<<(256 * 512 + 255) / 256, 256, 0, stream>>>(linW, btLhi, btLlo, 512, NCLS, 256);

    // ---- layer-0 input decomposition ----
    decomp4_kernel<<<((size_t)MPAD_P * 1024 / 4 + 255) / 256, 256, 0, stream>>>(
        (const float4*)x_paper, (ushort4*)AhiP, (ushort4*)AloP, NP, 1024, MPAD_P);
    decomp4_kernel<<<((size_t)MPAD_A * 1024 / 4 + 255) / 256, 256, 0, stream>>>(
        (const float4*)x_author, (ushort4*)AhiA, (ushort4*)AloA, NA, 1024, MPAD_A);

    auto gemm = [&](const unsigned short* Ah, const unsigned short* Al,
                    const unsigned short* Bh, const unsigned short* Bl,
                    const float* bias, float* C, int M, int Mpad, int K, int gx,
                    int Nstore, int ldc) {
        dim3 g(gx, Mpad / 256);
        gemm_ring<<<g, 512, 131072, stream>>>(Ah, Al, Bh, Bl, bias, C, M, K, Nstore, ldc);
    };

    const float* hp = x_paper;
    const float* ha = x_author;
    for (int l = 0; l < 3; ++l) {
        int K = Ks[l];
        float* hp_n = (l & 1) ? hpB : hpA;
        float* ha_n = (l & 1) ? haB : haA;
        float* zbuf_w = ha_n;  // alias: dead before agg_author writes ha_n
        const float* W = Wl[l];
        const float* al = alL[l];
        const float* ar = arL[l];
        size_t wstride = (size_t)K * 512;
        int relu = (l < 2) ? 1 : 0;

        // t0 (cites, paper z) and t1 (writes, author z) GEMMs
        gemm(AhiP, AloP, bthi[l][0], btlo[l][0], nullptr, zbuf, NP, MPAD_P, K, 2, 512, 512);
        gemm(AhiA, AloA, bthi[l][1], btlo[l][1], nullptr, zbuf_w, NA, MPAD_A, K, 2, 512, 512);
        // attention logits
        eler_kernel<<<(NP + 3) / 4, 256, 0, stream>>>(zbuf, al, ar, elA, erA, NP);
        eler_kernel<<<(NA + 3) / 4, 256, 0, stream>>>(zbuf_w, al + 512, nullptr, elB, nullptr, NA);
        fold_kernel<<<(K * 4 + 255) / 256, 256, 0, stream>>>(W + wstride, ar + 512, vfold, K);
        skinny_kernel<<<(NP + 3) / 4, 256, 0, stream>>>(hp, vfold, erB, NP, K);
        // paper aggregation: cites + writes fused (+relu)
        agg_fused<<<(NP + 3) / 4, 256, 0, stream>>>(
            rp_c, col_c, zbuf, elA, erA,
            rp_w, col_w, zbuf_w, elB, erB,
            hp_n, nullptr, nullptr, NP, relu);
        // t2 (wb, paper z) GEMM — must read old AhiP before decomp overwrites
        gemm(AhiP, AloP, bthi[l][2], btlo[l][2], nullptr, zbuf, NP, MPAD_P, K, 2, 512, 512);
        // paper decomp for next layer / final linear
        decomp4_kernel<<<((size_t)MPAD_P * 512 / 4 + 255) / 256, 256, 0, stream>>>(
            (const float4*)hp_n, (ushort4*)AhiP, (ushort4*)AloP, NP, 512, MPAD_P);
        // author aggregation (wb) (+relu +fused decomp)
        eler_kernel<<<(NP + 3) / 4, 256, 0, stream>>>(zbuf, al + 1024, nullptr, elA, nullptr, NP);
        fold_kernel<<<(K * 4 + 255) / 256, 256, 0, stream>>>(W + 2 * wstride, ar + 1024, vfold, K);
        skinny_kernel<<<(NA + 3) / 4, 256, 0, stream>>>(ha, vfold, erA, NA, K);
        agg_fused<<<(NA + 3) / 4, 256, 0, stream>>>(
            rp_b, col_b, zbuf, elA, erA,
            nullptr, nullptr, nullptr, nullptr, nullptr,
            ha_n, (l < 2) ? AhiA : nullptr, (l < 2) ? AloA : nullptr, NA, relu);
        hp = hp_n;
        ha = ha_n;
    }
    // ---- final linear ----
    gemm(AhiP, AloP, btLhi, btLlo, linb, out, NP, MPAD_P, 512, 1, NCLS, NCLS);
}

// Round 2
// 3317.503 us; speedup vs baseline: 1.0178x; 1.0178x over previous
//
#include <hip/hip_runtime.h>
#include <cstddef>
#include <cstdint>

// ---------------- problem constants (match reference) ----------------
static constexpr int NP = 60000, NA = 30000;
static constexpr int EC = 300000, EW = 150000, EB = 150000;
static constexpr int IN_F = 1024, HID = 512, H = 4, D = 128, NCLS = 153;
static constexpr int MPAD_P = 60160;  // 235 * 256
static constexpr int MPAD_A = 30208;  // 118 * 256

typedef __attribute__((ext_vector_type(8))) short short8;
typedef __attribute__((ext_vector_type(4))) float float4v;

// ---------------- bf16 helpers (RNE) ----------------
__device__ __forceinline__ unsigned short f2bf(float f) {
    unsigned int u = __float_as_uint(f);
    unsigned int r = u + 0x7FFFu + ((u >> 16) & 1u);
    return (unsigned short)(r >> 16);
}
__device__ __forceinline__ float bf2f(unsigned short h) {
    return __uint_as_float(((unsigned int)h) << 16);
}

// async global->LDS, 16B per lane; lds base must be wave-uniform
__device__ __forceinline__ void gll16(const unsigned short* g, unsigned short* l) {
    __builtin_amdgcn_global_load_lds(
        (const __attribute__((address_space(1))) unsigned int*)g,
        (__attribute__((address_space(3))) unsigned int*)l, 16, 0, 0);
}

// ---------------- CSR build ----------------
__global__ void hist_kernel(const int* __restrict__ dst, int E, int* __restrict__ counts) {
    int e = blockIdx.x * 256 + threadIdx.x;
    if (e < E) atomicAdd(&counts[dst[e]], 1);
}

__global__ void exscan_kernel(const int* __restrict__ in, int* __restrict__ out, int n) {
    __shared__ int wsum[4];
    int t = threadIdx.x;
    int lane = t & 63, w = t >> 6;
    int carry = 0;
    const int CH = 256 * 8;
    for (int base = 0; base < n; base += CH) {
        int v[8], run[8];
        int i0 = base + t * 8;
        int tsum = 0;
#pragma unroll
        for (int j = 0; j < 8; ++j) {
            int i = i0 + j;
            v[j] = (i < n) ? in[i] : 0;
            tsum += v[j];
            run[j] = tsum;
        }
        int x = tsum;
#pragma unroll
        for (int off = 1; off < 64; off <<= 1) {
            int y = __shfl_up(x, off);
            if (lane >= off) x += y;
        }
        if (lane == 63) wsum[w] = x;
        __syncthreads();
        int wpre = 0;
        for (int ww = 0; ww < w; ++ww) wpre += wsum[ww];
        int chunktot = wsum[0] + wsum[1] + wsum[2] + wsum[3];
        int pre = carry + wpre + (x - tsum);
#pragma unroll
        for (int j = 0; j < 8; ++j) {
            int i = i0 + j;
            if (i < n) out[i] = pre + run[j] - v[j];
        }
        carry += chunktot;
        __syncthreads();
    }
    if (t == 0) out[n] = carry;
}

__global__ void fill_kernel(const int* __restrict__ src, const int* __restrict__ dst, int E,
                            int* __restrict__ cursor, int* __restrict__ col) {
    int e = blockIdx.x * 256 + threadIdx.x;
    if (e < E) {
        int pos = atomicAdd(&cursor[dst[e]], 1);
        col[pos] = src[e];
    }
}

// ---------------- split-bf16 prep ----------------
__global__ void decomp4_kernel(const float4* __restrict__ x, ushort4* __restrict__ hi,
                               ushort4* __restrict__ lo, int M, int K, int Mpad) {
    size_t i4 = (size_t)blockIdx.x * 256 + threadIdx.x;
    size_t tot = ((size_t)Mpad * K) >> 2;
    if (i4 >= tot) return;
    size_t row = (i4 * 4) / (size_t)K;
    float4 v = make_float4(0.f, 0.f, 0.f, 0.f);
    if (row < (size_t)M) v = x[i4];
    ushort4 h, l;
    h.x = f2bf(v.x); h.y = f2bf(v.y); h.z = f2bf(v.z); h.w = f2bf(v.w);
    l.x = f2bf(v.x - bf2f(h.x)); l.y = f2bf(v.y - bf2f(h.y));
    l.z = f2bf(v.z - bf2f(h.z)); l.w = f2bf(v.w - bf2f(h.w));
    hi[i4] = h; lo[i4] = l;
}

// B (K x N, ld=N) -> BT hi/lo (Npad x K), zero pad rows
__global__ void btprep_kernel(const float* __restrict__ W, unsigned short* __restrict__ hi,
                              unsigned short* __restrict__ lo, int K, int N, int Npad) {
    int i = blockIdx.x * 256 + threadIdx.x;
    if (i >= Npad * K) return;
    int n = i / K, k = i - n * K;
    float v = (n < N) ? W[(size_t)k * N + n] : 0.f;
    unsigned short h = f2bf(v);
    hi[i] = h;
    lo[i] = f2bf(v - bf2f(h));
}

// ---------------- MFMA split-bf16 GEMM, 8-phase ring pipeline ----------------
// C = (Ahi+Alo)[MxK] @ (Bhi+Blo)^T via per-32-chunk segment sequence
//   seg0: Ahi*Bhi, seg1: Alo*Bhi, seg2: Ahi*Blo  (same accumulation order as 3-pass)
// Tile: BM=BN=256, virtual-BK=32, 8 waves (2Mx4N), per-wave 128x64 (8x4 frags).
// LDS: 4-slot ring x (A 256x32 + B 256x32) bf16 = 4 x 32KB = 128KB (dynamic).
// m201 cadence: each virtual K-tile = 2 phases of 16 MFMA:
//   PhA: ds_read fa[0..3]+fb[0..3] | 2 gll16 (A halves, t+3) | bar | mfma x16 | bar
//   PhB: ds_read fa2[0..3]         | 2 gll16 (B halves, t+3) | bar | mfma x16 |
//        s_waitcnt vmcnt(8) | bar      (counted: slots t+2,t+3 stay in flight)
// LDS swizzle (verified 0-conflict in R1): 16B chunk' = chunk ^ ((row>>1)&3),
// pre-swizzled global source (write side) + swizzled ds_read addr (read side).
__global__ __launch_bounds__(512, 2) void gemm_8ph(
    const unsigned short* __restrict__ Ahi, const unsigned short* __restrict__ Alo,
    const unsigned short* __restrict__ Bhi, const unsigned short* __restrict__ Blo,
    const float* __restrict__ bias, float* __restrict__ C,
    int M, int K, int Nstore, int ldc) {
    extern __shared__ unsigned short lds[];  // 4 * 16384 shorts
    const int tid = threadIdx.x;
    const int lane = tid & 63;
    const int w = tid >> 6;           // 8 waves
    const int wr = w >> 2, wc = w & 3;
    const int bm = blockIdx.y * 256, bn = blockIdx.x * 256;

    // ---- staging source (pre-swizzled 16B chunk): row = w*16 + (lane>>2) (+128)
    const int st_row = w * 16 + (lane >> 2);
    const int st_sc = (((lane & 3) ^ ((lane >> 3) & 3)) << 3);  // shorts
    const size_t aoff0 = (size_t)(bm + st_row) * K + st_sc;
    const size_t aoff1 = aoff0 + (size_t)128 * K;
    const size_t boff0 = (size_t)(bn + st_row) * K + st_sc;
    const size_t boff1 = boff0 + (size_t)128 * K;
    const int ldsA = w * 512;          // wave-uniform dest (shorts)
    const int ldsB = 8192 + w * 512;

    // ---- fragment read addressing (swizzled)
    const int arow = wr * 128 + (lane & 15);
    const int brow = wc * 64 + (lane & 15);
    const int rq = ((((lane >> 4) & 3) ^ ((lane >> 1) & 3)) << 3);
    const int aRead = arow * 32 + rq;
    const int bRead = 8192 + brow * 32 + rq;

    float4v acc[8][4];
    float4v zf = {0.f, 0.f, 0.f, 0.f};
#pragma unroll
    for (int i = 0; i < 8; ++i)
#pragma unroll
        for (int j = 0; j < 4; ++j) acc[i][j] = zf;

    auto STAGE_ALL = [&](unsigned rr, const unsigned short* As, const unsigned short* Bs, int kc) {
        unsigned short* sb = &lds[rr * 16384u];
        gll16(As + aoff0 + kc, sb + ldsA);
        gll16(As + aoff1 + kc, sb + ldsA + 4096);
        gll16(Bs + boff0 + kc, sb + ldsB);
        gll16(Bs + boff1 + kc, sb + ldsB + 4096);
    };

#define WAITV(n) asm volatile("s_waitcnt vmcnt(" #n ")" ::: "memory")
#define BARF()                                 \
    do {                                       \
        asm volatile("" ::: "memory");         \
        __builtin_amdgcn_s_barrier();          \
        asm volatile("" ::: "memory");         \
    } while (0)

// One virtual K-tile = 2 phases (m201 cadence). DOSTAGE is a literal 0/1.
// WAITSTMT runs after PhB's MFMA cluster, before the closing barrier.
#define TILE(RR, ASRC, BSRC, KN, DOSTAGE, WAITSTMT)                                   \
    do {                                                                              \
        const unsigned short* sb = &lds[(RR) * 16384u];                               \
        unsigned short* db = &lds[(((RR) + 3u) & 3u) * 16384u];                       \
        short8 fa[4], fb[4];                                                          \
        _Pragma("unroll") for (int i = 0; i < 4; ++i)                                 \
            fa[i] = *(const short8*)&sb[aRead + i * 512];                             \
        _Pragma("unroll") for (int j = 0; j < 4; ++j)                                 \
            fb[j] = *(const short8*)&sb[bRead + j * 512];                             \
        if (DOSTAGE) {                                                                \
            gll16(ASRC + aoff0 + (KN), db + ldsA);                                    \
            gll16(ASRC + aoff1 + (KN), db + ldsA + 4096);                             \
        }                                                                             \
        BARF();                                                                       \
        __builtin_amdgcn_s_setprio(1);                                                \
        _Pragma("unroll") for (int i = 0; i < 4; ++i)                                 \
            _Pragma("unroll") for (int j = 0; j < 4; ++j)                             \
                acc[i][j] = __builtin_amdgcn_mfma_f32_16x16x32_bf16(fa[i], fb[j], acc[i][j], 0, 0, 0); \
        __builtin_amdgcn_s_setprio(0);                                                \
        BARF();                                                                       \
        short8 fa2[4];                                                                \
        _Pragma("unroll") for (int i = 0; i < 4; ++i)                                 \
            fa2[i] = *(const short8*)&sb[aRead + (i + 4) * 512];                      \
        if (DOSTAGE) {                                                                \
            gll16(BSRC + boff0 + (KN), db + ldsB);                                    \
            gll16(BSRC + boff1 + (KN), db + ldsB + 4096);                             \
        }                                                                             \
        BARF();                                                                       \
        __builtin_amdgcn_s_setprio(1);                                                \
        _Pragma("unroll") for (int i = 0; i < 4; ++i)                                 \
            _Pragma("unroll") for (int j = 0; j < 4; ++j)                             \
                acc[i + 4][j] = __builtin_amdgcn_mfma_f32_16x16x32_bf16(fa2[i], fb[j], acc[i + 4][j], 0, 0, 0); \
        __builtin_amdgcn_s_setprio(0);                                                \
        WAITSTMT;                                                                     \
        BARF();                                                                       \
    } while (0)

    // prologue: stage chunk 0, all 3 segments, into ring slots 0,1,2 (12 loads),
    // then wait for slot 0's 4 loads and sync before the first reads.
    STAGE_ALL(0, Ahi, Bhi, 0);
    STAGE_ALL(1, Alo, Bhi, 0);
    STAGE_ALL(2, Ahi, Blo, 0);
    WAITV(8);
    BARF();

    unsigned rg = 0;
    const int nK = K >> 5;  // 32-wide k-chunks
#pragma unroll 1
    for (int c = 0; c < nK - 1; ++c) {
        const int kn = (c + 1) << 5;
        TILE(rg, Ahi, Bhi, kn, 1, WAITV(8));
        rg = (rg + 1) & 3;
        TILE(rg, Alo, Bhi, kn, 1, WAITV(8));
        rg = (rg + 1) & 3;
        TILE(rg, Ahi, Blo, kn, 1, WAITV(8));
        rg = (rg + 1) & 3;
    }
    // epilogue chunk (tiles T-3..T-1): no staging; drain 4 -> 0 -> none
    TILE(rg, Ahi, Bhi, 0, 0, WAITV(4));
    rg = (rg + 1) & 3;
    TILE(rg, Alo, Bhi, 0, 0, WAITV(0));
    rg = (rg + 1) & 3;
    TILE(rg, Ahi, Blo, 0, 0, (void)0);
#undef TILE
#undef WAITV
#undef BARF

    // C/D layout: col = lane&15, row = (lane>>4)*4 + reg
    const int col0 = bn + wc * 64 + (lane & 15);
    const int row0 = bm + wr * 128 + ((lane >> 4) << 2);
#pragma unroll
    for (int i = 0; i < 8; ++i) {
#pragma unroll
        for (int j = 0; j < 4; ++j) {
            int col = col0 + j * 16;
            if (col >= Nstore) continue;
            float badd = bias ? bias[col] : 0.f;
            int rowb = row0 + i * 16;
#pragma unroll
            for (int k = 0; k < 4; ++k) {
                int row = rowb + k;
                if (row < M) C[(size_t)row * ldc + col] = acc[i][j][k] + badd;
            }
        }
    }
}

// ---------------- el / er from z (one wave per row) ----------------
__global__ __launch_bounds__(256) void eler_kernel(
    const float* __restrict__ z, const float* __restrict__ al, const float* __restrict__ ar,
    float* __restrict__ el, float* __restrict__ er, int M) {
    int row = blockIdx.x * 4 + (threadIdx.x >> 6);
    int lane = threadIdx.x & 63;
    if (row >= M) return;
    const float4* zr = (const float4*)(z + (size_t)row * 512 + lane * 8);
    float4 z0 = zr[0], z1 = zr[1];
    const float4* alp = (const float4*)(al + lane * 8);
    float4 a0 = alp[0], a1 = alp[1];
    float s = z0.x * a0.x + z0.y * a0.y + z0.z * a0.z + z0.w * a0.w
            + z1.x * a1.x + z1.y * a1.y + z1.z * a1.z + z1.w * a1.w;
    s += __shfl_xor(s, 8); s += __shfl_xor(s, 4); s += __shfl_xor(s, 2); s += __shfl_xor(s, 1);
    int h = lane >> 4;
    if ((lane & 15) == 0) el[(size_t)row * 4 + h] = s;
    if (er) {
        const float4* arp = (const float4*)(ar + lane * 8);
        float4 b0 = arp[0], b1 = arp[1];
        float t = z0.x * b0.x + z0.y * b0.y + z0.z * b0.z + z0.w * b0.w
                + z1.x * b1.x + z1.y * b1.y + z1.z * b1.z + z1.w * b1.w;
        t += __shfl_xor(t, 8); t += __shfl_xor(t, 4); t += __shfl_xor(t, 2); t += __shfl_xor(t, 1);
        if ((lane & 15) == 0) er[(size_t)row * 4 + h] = t;
    }
}

// ---------------- fold: v[k,h] = sum_d W[k, h*128+d] * ar[h,d] ----------------
__global__ void fold_kernel(const float* __restrict__ W, const float* __restrict__ ar,
                            float* __restrict__ v, int K) {
    int i = blockIdx.x * 256 + threadIdx.x;
    if (i >= K * 4) return;
    int k = i >> 2, h = i & 3;
    const float* wr = W + (size_t)k * 512 + h * 128;
    const float* a = ar + h * 128;
    float s = 0.f;
#pragma unroll 4
    for (int d = 0; d < 128; ++d) s += wr[d] * a[d];
    v[i] = s;
}

// ---------------- skinny: er[M,4] = h[M,K] @ v[K,4] ----------------
__global__ __launch_bounds__(256) void skinny_kernel(
    const float* __restrict__ h, const float* __restrict__ v,
    float* __restrict__ er, int M, int K) {
    __shared__ float vs[4096];
    for (int i = threadIdx.x; i < K * 4; i += 256) vs[i] = v[i];
    __syncthreads();
    int row = blockIdx.x * 4 + (threadIdx.x >> 6);
    int lane = threadIdx.x & 63;
    if (row >= M) return;
    const float* hr = h + (size_t)row * K;
    float a0 = 0, a1 = 0, a2 = 0, a3 = 0;
    for (int k = lane; k < K; k += 64) {
        float x = hr[k];
        float4 vv = *(const float4*)&vs[k * 4];
        a0 += x * vv.x; a1 += x * vv.y; a2 += x * vv.z; a3 += x * vv.w;
    }
#pragma unroll
    for (int off = 32; off; off >>= 1) {
        a0 += __shfl_xor(a0, off); a1 += __shfl_xor(a1, off);
        a2 += __shfl_xor(a2, off); a3 += __shfl_xor(a3, off);
    }
    if (lane == 0) *(float4*)&er[(size_t)row * 4] = make_float4(a0, a1, a2, a3);
}

// ---------------- fused softmax-stats + aggregation (+relu +decomp) ----------------
__global__ __launch_bounds__(256) void agg_fused(
    const int* __restrict__ rp1, const int* __restrict__ col1, const float* __restrict__ z1,
    const float* __restrict__ el1, const float* __restrict__ er1,
    const int* __restrict__ rp2, const int* __restrict__ col2, const float* __restrict__ z2,
    const float* __restrict__ el2, const float* __restrict__ er2,
    float* __restrict__ out, unsigned short* __restrict__ hi, unsigned short* __restrict__ lo,
    int N, int do_relu) {
    int j = blockIdx.x * 4 + (threadIdx.x >> 6);
    int lane = threadIdx.x & 63;
    if (j >= N) return;
    int h = lane >> 4;
    float4 acc0 = make_float4(0, 0, 0, 0), acc1 = make_float4(0, 0, 0, 0);

    // ---- type 1 ----
    {
        int e0 = rp1[j], e1 = rp1[j + 1];
        float erh = er1[(size_t)j * 4 + h];
        float m = -INFINITY, s = 0.f;
        for (int e = e0; e < e1; ++e) {
            float x = el1[(size_t)col1[e] * 4 + h] + erh;
            x = (x >= 0.f) ? x : 0.2f * x;
            float mn = fmaxf(m, x);
            s = s * expf(m - mn) + expf(x - mn);
            m = mn;
        }
        float inv = 1.0f / (s + 1e-9f);
        for (int e = e0; e < e1; ++e) {
            int src = col1[e];
            float x = el1[(size_t)src * 4 + h] + erh;
            x = (x >= 0.f) ? x : 0.2f * x;
            float wgt = expf(x - m) * inv;
            const float4* zr = (const float4*)(z1 + (size_t)src * 512 + lane * 8);
            float4 za = zr[0], zb = zr[1];
            acc0.x += wgt * za.x; acc0.y += wgt * za.y; acc0.z += wgt * za.z; acc0.w += wgt * za.w;
            acc1.x += wgt * zb.x; acc1.y += wgt * zb.y; acc1.z += wgt * zb.z; acc1.w += wgt * zb.w;
        }
    }
    // ---- type 2 (optional) ----
    if (rp2) {
        int e0 = rp2[j], e1 = rp2[j + 1];
        float erh = er2[(size_t)j * 4 + h];
        float m = -INFINITY, s = 0.f;
        for (int e = e0; e < e1; ++e) {
            float x = el2[(size_t)col2[e] * 4 + h] + erh;
            x = (x >= 0.f) ? x : 0.2f * x;
            float mn = fmaxf(m, x);
            s = s * expf(m - mn) + expf(x - mn);
            m = mn;
        }
        float inv = 1.0f / (s + 1e-9f);
        for (int e = e0; e < e1; ++e) {
            int src = col2[e];
            float x = el2[(size_t)src * 4 + h] + erh;
            x = (x >= 0.f) ? x : 0.2f * x;
            float wgt = expf(x - m) * inv;
            const float4* zr = (const float4*)(z2 + (size_t)src * 512 + lane * 8);
            float4 za = zr[0], zb = zr[1];
            acc0.x += wgt * za.x; acc0.y += wgt * za.y; acc0.z += wgt * za.z; acc0.w += wgt * za.w;
            acc1.x += wgt * zb.x; acc1.y += wgt * zb.y; acc1.z += wgt * zb.z; acc1.w += wgt * zb.w;
        }
    }
    if (do_relu) {
        acc0.x = fmaxf(acc0.x, 0.f); acc0.y = fmaxf(acc0.y, 0.f);
        acc0.z = fmaxf(acc0.z, 0.f); acc0.w = fmaxf(acc0.w, 0.f);
        acc1.x = fmaxf(acc1.x, 0.f); acc1.y = fmaxf(acc1.y, 0.f);
        acc1.w = fmaxf(acc1.w, 0.f); acc1.z = fmaxf(acc1.z, 0.f);
    }
    float* op = out + (size_t)j * 512 + lane * 8;
    *(float4*)op = acc0;
    *(float4*)(op + 4) = acc1;
    if (hi) {
        size_t base = (size_t)j * 512 + lane * 8;
        ushort4 h0, h1, l0, l1;
        h0.x = f2bf(acc0.x); h0.y = f2bf(acc0.y); h0.z = f2bf(acc0.z); h0.w = f2bf(acc0.w);
        h1.x = f2bf(acc1.x); h1.y = f2bf(acc1.y); h1.z = f2bf(acc1.z); h1.w = f2bf(acc1.w);
        l0.x = f2bf(acc0.x - bf2f(h0.x)); l0.y = f2bf(acc0.y - bf2f(h0.y));
        l0.z = f2bf(acc0.z - bf2f(h0.z)); l0.w = f2bf(acc0.w - bf2f(h0.w));
        l1.x = f2bf(acc1.x - bf2f(h1.x)); l1.y = f2bf(acc1.y - bf2f(h1.y));
        l1.z = f2bf(acc1.z - bf2f(h1.z)); l1.w = f2bf(acc1.w - bf2f(h1.w));
        *(ushort4*)(hi + base) = h0;
        *(ushort4*)(hi + base + 4) = h1;
        *(ushort4*)(lo + base) = l0;
        *(ushort4*)(lo + base + 4) = l1;
    }
}

// ---------------- launcher ----------------
extern "C" void kernel_launch(void* const* d_in, const int* in_sizes, int n_in,
                              void* d_out, int out_size, void* d_ws, size_t ws_size,
                              hipStream_t stream) {
    const float* x_paper = (const float*)d_in[0];
    const float* x_author = (const float*)d_in[1];
    const int* cites_src = (const int*)d_in[2];
    const int* cites_dst = (const int*)d_in[3];
    const int* writes_src = (const int*)d_in[4];
    const int* writes_dst = (const int*)d_in[5];
    const int* wb_src = (const int*)d_in[6];
    const int* wb_dst = (const int*)d_in[7];
    const float* W0 = (const float*)d_in[8];
    const float* al0 = (const float*)d_in[9];
    const float* ar0 = (const float*)d_in[10];
    const float* W1 = (const float*)d_in[11];
    const float* al1 = (const float*)d_in[12];
    const float* ar1 = (const float*)d_in[13];
    const float* W2 = (const float*)d_in[14];
    const float* al2 = (const float*)d_in[15];
    const float* ar2 = (const float*)d_in[16];
    const float* linW = (const float*)d_in[17];
    const float* linb = (const float*)d_in[18];
    float* out = (float*)d_out;

    // allow 128KB dynamic LDS for the ring GEMM (host-side, capture-safe)
    (void)hipFuncSetAttribute((const void*)gemm_8ph,
                              hipFuncAttributeMaxDynamicSharedMemorySize, 131072);

    char* p = (char*)d_ws;
    auto alloc = [&](size_t n) { char* r = p; p += (n + 255) & ~(size_t)255; return r; };

    float* hpA = (float*)alloc((size_t)NP * 512 * 4);
    float* hpB = (float*)alloc((size_t)NP * 512 * 4);
    float* haA = (float*)alloc((size_t)NA * 512 * 4);
    float* haB = (float*)alloc((size_t)NA * 512 * 4);
    float* zbuf = (float*)alloc((size_t)NP * 512 * 4);   // paper-source z
    float* elA = (float*)alloc((size_t)NP * 16);
    float* erA = (float*)alloc((size_t)NP * 16);
    float* elB = (float*)alloc((size_t)NP * 16);
    float* erB = (float*)alloc((size_t)NP * 16);
    float* vfold = (float*)alloc(4096 * 4);
    int* rp_c = (int*)alloc((NP + 1) * 4);
    int* col_c = (int*)alloc((size_t)EC * 4);
    int* rp_w = (int*)alloc((NP + 1) * 4);
    int* col_w = (int*)alloc((size_t)EW * 4);
    int* rp_b = (int*)alloc((NA + 1) * 4);
    int* col_b = (int*)alloc((size_t)EB * 4);
    int* cursor = (int*)alloc((NP + 1) * 4);
    int* counts = (int*)alloc((size_t)NP * 4);

    unsigned short* AhiP = (unsigned short*)alloc((size_t)MPAD_P * 1024 * 2);
    unsigned short* AloP = (unsigned short*)alloc((size_t)MPAD_P * 1024 * 2);
    unsigned short* AhiA = (unsigned short*)alloc((size_t)MPAD_A * 1024 * 2);
    unsigned short* AloA = (unsigned short*)alloc((size_t)MPAD_A * 1024 * 2);
    const int Ks[3] = {IN_F, HID, HID};
    unsigned short *bthi[3][3], *btlo[3][3];
    for (int l = 0; l < 3; ++l)
        for (int t = 0; t < 3; ++t) {
            bthi[l][t] = (unsigned short*)alloc((size_t)512 * Ks[l] * 2);
            btlo[l][t] = (unsigned short*)alloc((size_t)512 * Ks[l] * 2);
        }
    unsigned short* btLhi = (unsigned short*)alloc((size_t)256 * 512 * 2);
    unsigned short* btLlo = (unsigned short*)alloc((size_t)256 * 512 * 2);
    (void)ws_size;

    // ---- CSR build ----
    struct EdgeT { const int* src; const int* dst; int E; int n; int* rp; int* col; };
    EdgeT ets[3] = {
        {cites_src, cites_dst, EC, NP, rp_c, col_c},
        {writes_src, writes_dst, EW, NP, rp_w, col_w},
        {wb_src, wb_dst, EB, NA, rp_b, col_b},
    };
    for (int t = 0; t < 3; ++t) {
        hipMemsetAsync(counts, 0, (size_t)ets[t].n * 4, stream);
        hist_kernel<<<(ets[t].E + 255) / 256, 256, 0, stream>>>(ets[t].dst, ets[t].E, counts);
        exscan_kernel<<<1, 256, 0, stream>>>(counts, ets[t].rp, ets[t].n);
        hipMemcpyAsync(cursor, ets[t].rp, (size_t)ets[t].n * 4, hipMemcpyDeviceToDevice, stream);
        fill_kernel<<<(ets[t].E + 255) / 256, 256, 0, stream>>>(ets[t].src, ets[t].dst, ets[t].E, cursor, ets[t].col);
    }

    const float* Wl[3] = {W0, W1, W2};
    const float* alL[3] = {al0, al1, al2};
    const float* arL[3] = {ar0, ar1, ar2};

    // ---- weight transpose + hi/lo decomposition ----
    for (int l = 0; l < 3; ++l) {
        int K = Ks[l];
        for (int t = 0; t < 3; ++t)
            btprep_kernel<<<(512 * K + 255) / 256, 256, 0, stream>>>(
                Wl[l] + (size_t)t * K * 512, bthi[l][t], btlo[l][t], K, 512, 512);
    }
    btprep_kernel<<<(256 * 512 + 255) / 256, 256, 0, stream>>>(linW, btLhi, btLlo, 512, NCLS, 256);

    // ---- layer-0 input decomposition ----
    decomp4_kernel<<<((size_t)MPAD_P * 1024 / 4 + 255) / 256, 256, 0, stream>>>(
        (const float4*)x_paper, (ushort4*)AhiP, (ushort4*)AloP, NP, 1024, MPAD_P);
    decomp4_kernel<<<((size_t)MPAD_A * 1024 / 4 + 255) / 256, 256, 0, stream>>>(
        (const float4*)x_author, (ushort4*)AhiA, (ushort4*)AloA, NA, 1024, MPAD_A);

    auto gemm = [&](const unsigned short* Ah, const unsigned short* Al,
                    const unsigned short* Bh, const unsigned short* Bl,
                    const float* bias, float* C, int M, int Mpad, int K, int gx,
                    int Nstore, int ldc) {
        dim3 g(gx, Mpad / 256);
        gemm_8ph<<<g, 512, 131072, stream>>>(Ah, Al, Bh, Bl, bias, C, M, K, Nstore, ldc);
    };

    const float* hp = x_paper;
    const float* ha = x_author;
    for (int l = 0; l < 3; ++l) {
        int K = Ks[l];
        float* hp_n = (l & 1) ? hpB : hpA;
        float* ha_n = (l & 1) ? haB : haA;
        float* zbuf_w = ha_n;  // alias: dead before agg_author writes ha_n
        const float* W = Wl[l];
        const float* al = alL[l];
        const float* ar = arL[l];
        size_t wstride = (size_t)K * 512;
        int relu = (l < 2) ? 1 : 0;

        // t0 (cites, paper z) and t1 (writes, author z) GEMMs
        gemm(AhiP, AloP, bthi[l][0], btlo[l][0], nullptr, zbuf, NP, MPAD_P, K, 2, 512, 512);
        gemm(AhiA, AloA, bthi[l][1], btlo[l][1], nullptr, zbuf_w, NA, MPAD_A, K, 2, 512, 512);
        // attention logits
        eler_kernel<<<(NP + 3) / 4, 256, 0, stream>>>(zbuf, al, ar, elA, erA, NP);
        eler_kernel<<<(NA + 3) / 4, 256, 0, stream>>>(zbuf_w, al + 512, nullptr, elB, nullptr, NA);
        fold_kernel<<<(K * 4 + 255) / 256, 256, 0, stream>>>(W + wstride, ar + 512, vfold, K);
        skinny_kernel<<<(NP + 3) / 4, 256, 0, stream>>>(hp, vfold, erB, NP, K);
        // paper aggregation: cites + writes fused (+relu)
        agg_fused<<<(NP + 3) / 4, 256, 0, stream>>>(
            rp_c, col_c, zbuf, elA, erA,
            rp_w, col_w, zbuf_w, elB, erB,
            hp_n, nullptr, nullptr, NP, relu);
        // t2 (wb, paper z) GEMM — must read old AhiP before decomp overwrites
        gemm(AhiP, AloP, bthi[l][2], btlo[l][2], nullptr, zbuf, NP, MPAD_P, K, 2, 512, 512);
        // paper decomp for next layer / final linear
        decomp4_kernel<<<((size_t)MPAD_P * 512 / 4 + 255) / 256, 256, 0, stream>>>(
            (const float4*)hp_n, (ushort4*)AhiP, (ushort4*)AloP, NP, 512, MPAD_P);
        // author aggregation (wb) (+relu +fused decomp)
        eler_kernel<<<(NP + 3) / 4, 256, 0, stream>>>(zbuf, al + 1024, nullptr, elA, nullptr, NP);
        fold_kernel<<<(K * 4 + 255) / 256, 256, 0, stream>>>(W + 2 * wstride, ar + 1024, vfold, K);
        skinny_kernel<<<(NA + 3) / 4, 256, 0, stream>>>(ha, vfold, erA, NA, K);
        agg_fused<<<(NA + 3) / 4, 256, 0, stream>>>(
            rp_b, col_b, zbuf, elA, erA,
            nullptr, nullptr, nullptr, nullptr, nullptr,
            ha_n, (l < 2) ? AhiA : nullptr, (l < 2) ? AloA : nullptr, NA, relu);
        hp = hp_n;
        ha = ha_n;
    }
    // ---- final linear ----
    gemm(AhiP, AloP, btLhi, btLlo, linb, out, NP, MPAD_P, 512, 1, NCLS, NCLS);
}

// Round 3
// 3215.789 us; speedup vs baseline: 1.0500x; 1.0316x over previous
//
#include <hip/hip_runtime.h>
#include <cstddef>
#include <cstdint>

// ---------------- problem constants (match reference) ----------------
static constexpr int NP = 60000, NA = 30000;
static constexpr int EC = 300000, EW = 150000, EB = 150000;
static constexpr int IN_F = 1024, HID = 512, H = 4, D = 128, NCLS = 153;
static constexpr int MPAD_P = 60160;  // 235 * 256
static constexpr int MPAD_A = 30208;  // 118 * 256

typedef __attribute__((ext_vector_type(8))) short short8;
typedef __attribute__((ext_vector_type(4))) float float4v;

// ---------------- bf16 helpers (RNE) ----------------
__device__ __forceinline__ unsigned short f2bf(float f) {
    unsigned int u = __float_as_uint(f);
    unsigned int r = u + 0x7FFFu + ((u >> 16) & 1u);
    return (unsigned short)(r >> 16);
}
__device__ __forceinline__ float bf2f(unsigned short h) {
    return __uint_as_float(((unsigned int)h) << 16);
}

// async global->LDS, 16B per lane; lds base must be wave-uniform
__device__ __forceinline__ void gll16(const unsigned short* g, unsigned short* l) {
    __builtin_amdgcn_global_load_lds(
        (const __attribute__((address_space(1))) unsigned int*)g,
        (__attribute__((address_space(3))) unsigned int*)l, 16, 0, 0);
}

// ---------------- CSR build ----------------
__global__ void hist_kernel(const int* __restrict__ dst, int E, int* __restrict__ counts) {
    int e = blockIdx.x * 256 + threadIdx.x;
    if (e < E) atomicAdd(&counts[dst[e]], 1);
}

__global__ void exscan_kernel(const int* __restrict__ in, int* __restrict__ out, int n) {
    __shared__ int wsum[4];
    int t = threadIdx.x;
    int lane = t & 63, w = t >> 6;
    int carry = 0;
    const int CH = 256 * 8;
    for (int base = 0; base < n; base += CH) {
        int v[8], run[8];
        int i0 = base + t * 8;
        int tsum = 0;
#pragma unroll
        for (int j = 0; j < 8; ++j) {
            int i = i0 + j;
            v[j] = (i < n) ? in[i] : 0;
            tsum += v[j];
            run[j] = tsum;
        }
        int x = tsum;
#pragma unroll
        for (int off = 1; off < 64; off <<= 1) {
            int y = __shfl_up(x, off);
            if (lane >= off) x += y;
        }
        if (lane == 63) wsum[w] = x;
        __syncthreads();
        int wpre = 0;
        for (int ww = 0; ww < w; ++ww) wpre += wsum[ww];
        int chunktot = wsum[0] + wsum[1] + wsum[2] + wsum[3];
        int pre = carry + wpre + (x - tsum);
#pragma unroll
        for (int j = 0; j < 8; ++j) {
            int i = i0 + j;
            if (i < n) out[i] = pre + run[j] - v[j];
        }
        carry += chunktot;
        __syncthreads();
    }
    if (t == 0) out[n] = carry;
}

__global__ void fill_kernel(const int* __restrict__ src, const int* __restrict__ dst, int E,
                            int* __restrict__ cursor, int* __restrict__ col) {
    int e = blockIdx.x * 256 + threadIdx.x;
    if (e < E) {
        int pos = atomicAdd(&cursor[dst[e]], 1);
        col[pos] = src[e];
    }
}

// ---------------- split-bf16 prep ----------------
__global__ void decomp4_kernel(const float4* __restrict__ x, ushort4* __restrict__ hi,
                               ushort4* __restrict__ lo, int M, int K, int Mpad) {
    size_t i4 = (size_t)blockIdx.x * 256 + threadIdx.x;
    size_t tot = ((size_t)Mpad * K) >> 2;
    if (i4 >= tot) return;
    size_t row = (i4 * 4) / (size_t)K;
    float4 v = make_float4(0.f, 0.f, 0.f, 0.f);
    if (row < (size_t)M) v = x[i4];
    ushort4 h, l;
    h.x = f2bf(v.x); h.y = f2bf(v.y); h.z = f2bf(v.z); h.w = f2bf(v.w);
    l.x = f2bf(v.x - bf2f(h.x)); l.y = f2bf(v.y - bf2f(h.y));
    l.z = f2bf(v.z - bf2f(h.z)); l.w = f2bf(v.w - bf2f(h.w));
    hi[i4] = h; lo[i4] = l;
}

// B (K x N, ld=N) -> BT hi/lo (Npad x K), zero pad rows
__global__ void btprep_kernel(const float* __restrict__ W, unsigned short* __restrict__ hi,
                              unsigned short* __restrict__ lo, int K, int N, int Npad) {
    int i = blockIdx.x * 256 + threadIdx.x;
    if (i >= Npad * K) return;
    int n = i / K, k = i - n * K;
    float v = (n < N) ? W[(size_t)k * N + n] : 0.f;
    unsigned short h = f2bf(v);
    hi[i] = h;
    lo[i] = f2bf(v - bf2f(h));
}

// ---------------- MFMA split-bf16 GEMM, fragment-reuse 6-phase pipeline ----------
// C = (Ahi+Alo)[MxK] @ (Bhi+Blo)^T. Per 32-k chunk, 3 MFMA segments:
//   seg0: Ahi*Bhi, seg1: Alo*Bhi, seg2: Ahi*Blo  (order preserved per acc element)
// KEY (R2 post-mortem): previous version was LDS-BW-bound (~90% port util).
// Now fragments are read ONCE per chunk (fahi/falo/fbhi/fblo, 24 b128/wave vs 36)
// and each of Ahi/Bhi/Alo/Blo is staged ONCE (8 gll/wave vs 12):
// LDS traffic/chunk/CU: 192KB read + 64KB write = 2290 cyc < MFMA 3090 cyc.
// Ring: 4 slots = 2 chunk-pairs; chunk uses (hi-slot rg, lo-slot rg+1); stages
// next chunk into (rg^2, rg^2+1). Counted waits: WAITV(4) end-P2 + end-chunk.
// LDS swizzle (verified 0-conflict): 16B chunk' = chunk ^ ((row>>1)&3),
// pre-swizzled global source (write side) + swizzled ds_read addr (read side).
__global__ __launch_bounds__(512, 2) void gemm_6ph(
    const unsigned short* __restrict__ Ahi, const unsigned short* __restrict__ Alo,
    const unsigned short* __restrict__ Bhi, const unsigned short* __restrict__ Blo,
    const float* __restrict__ bias, float* __restrict__ C,
    int M, int K, int Nstore, int ldc) {
    extern __shared__ unsigned short lds[];  // 4 * 16384 shorts = 128KB
    const int tid = threadIdx.x;
    const int lane = tid & 63;
    const int w = tid >> 6;           // 8 waves
    const int wr = w >> 2, wc = w & 3;
    const int bm = blockIdx.y * 256, bn = blockIdx.x * 256;

    // ---- staging source (pre-swizzled 16B chunk): row = w*16 + (lane>>2) (+128)
    const int st_row = w * 16 + (lane >> 2);
    const int st_sc = (((lane & 3) ^ ((lane >> 3) & 3)) << 3);  // shorts
    const size_t aoff0 = (size_t)(bm + st_row) * K + st_sc;
    const size_t aoff1 = aoff0 + (size_t)128 * K;
    const size_t boff0 = (size_t)(bn + st_row) * K + st_sc;
    const size_t boff1 = boff0 + (size_t)128 * K;
    const int ldsAo = w * 512;          // within-slot offsets (shorts)
    const int ldsBo = 8192 + w * 512;

    // ---- fragment read addressing (swizzled)
    const int arow = wr * 128 + (lane & 15);
    const int brow = wc * 64 + (lane & 15);
    const int rq = ((((lane >> 4) & 3) ^ ((lane >> 1) & 3)) << 3);
    const int aRead = arow * 32 + rq;
    const int bRead = 8192 + brow * 32 + rq;

    float4v acc[8][4];
    float4v zf = {0.f, 0.f, 0.f, 0.f};
#pragma unroll
    for (int i = 0; i < 8; ++i)
#pragma unroll
        for (int j = 0; j < 4; ++j) acc[i][j] = zf;

#define WAITV(n) asm volatile("s_waitcnt vmcnt(" #n ")" ::: "memory")
#define BARF()                                 \
    do {                                       \
        asm volatile("" ::: "memory");         \
        __builtin_amdgcn_s_barrier();          \
        asm volatile("" ::: "memory");         \
    } while (0)
#define PRIO1 __builtin_amdgcn_s_setprio(1)
#define PRIO0 __builtin_amdgcn_s_setprio(0)
#define MF(a, b, c) __builtin_amdgcn_mfma_f32_16x16x32_bf16(a, b, c, 0, 0, 0)

// One 32-k chunk = 6 phases. Stage order (vmcnt!): Ahi,Bhi -> n0; Alo,Blo -> n1.
// W2STMT after P2 MFMA retires prev chunk's Alo/Blo; W6STMT after last MFMA
// retires this chunk's Ahi/Bhi stages (needed by next chunk's P1).
#define CHUNK(RG, DOSTAGE, KN, W2STMT, W6STMT)                                        \
    do {                                                                              \
        const unsigned short* sA = &lds[(RG) * 16384u];          /* hi pair slot */   \
        const unsigned short* sB = &lds[((RG) + 1u) * 16384u];   /* lo pair slot */   \
        unsigned short* dA = &lds[((RG) ^ 2u) * 16384u];                              \
        unsigned short* dB = &lds[(((RG) ^ 2u) + 1u) * 16384u];                       \
        short8 fahi[8], falo[8], fbhi[4], fblo[4];                                    \
        /* P1: seg0 lower */                                                          \
        _Pragma("unroll") for (int i = 0; i < 4; ++i)                                 \
            fahi[i] = *(const short8*)&sA[aRead + i * 512];                           \
        _Pragma("unroll") for (int j = 0; j < 4; ++j)                                 \
            fbhi[j] = *(const short8*)&sA[bRead + j * 512];                           \
        if (DOSTAGE) {                                                                \
            gll16(Ahi + aoff0 + (KN), dA + ldsAo);                                    \
            gll16(Ahi + aoff1 + (KN), dA + ldsAo + 4096);                             \
        }                                                                             \
        BARF(); PRIO1;                                                                \
        _Pragma("unroll") for (int i = 0; i < 4; ++i)                                 \
            _Pragma("unroll") for (int j = 0; j < 4; ++j)                             \
                acc[i][j] = MF(fahi[i], fbhi[j], acc[i][j]);                          \
        PRIO0; BARF();                                                                \
        /* P2: seg0 upper */                                                          \
        _Pragma("unroll") for (int i = 0; i < 4; ++i)                                 \
            fahi[i + 4] = *(const short8*)&sA[aRead + (i + 4) * 512];                 \
        if (DOSTAGE) {                                                                \
            gll16(Bhi + boff0 + (KN), dA + ldsBo);                                    \
            gll16(Bhi + boff1 + (KN), dA + ldsBo + 4096);                             \
        }                                                                             \
        BARF(); PRIO1;                                                                \
        _Pragma("unroll") for (int i = 0; i < 4; ++i)                                 \
            _Pragma("unroll") for (int j = 0; j < 4; ++j)                             \
                acc[i + 4][j] = MF(fahi[i + 4], fbhi[j], acc[i + 4][j]);              \
        PRIO0; W2STMT; BARF();                                                        \
        /* P3: seg1 lower */                                                          \
        _Pragma("unroll") for (int i = 0; i < 4; ++i)                                 \
            falo[i] = *(const short8*)&sB[aRead + i * 512];                           \
        if (DOSTAGE) {                                                                \
            gll16(Alo + aoff0 + (KN), dB + ldsAo);                                    \
            gll16(Alo + aoff1 + (KN), dB + ldsAo + 4096);                             \
        }                                                                             \
        BARF(); PRIO1;                                                                \
        _Pragma("unroll") for (int i = 0; i < 4; ++i)                                 \
            _Pragma("unroll") for (int j = 0; j < 4; ++j)                             \
                acc[i][j] = MF(falo[i], fbhi[j], acc[i][j]);                          \
        PRIO0; BARF();                                                                \
        /* P4: seg1 upper */                                                          \
        _Pragma("unroll") for (int i = 0; i < 4; ++i)                                 \
            falo[i + 4] = *(const short8*)&sB[aRead + (i + 4) * 512];                 \
        if (DOSTAGE) {                                                                \
            gll16(Blo + boff0 + (KN), dB + ldsBo);                                    \
            gll16(Blo + boff1 + (KN), dB + ldsBo + 4096);                             \
        }                                                                             \
        BARF(); PRIO1;                                                                \
        _Pragma("unroll") for (int i = 0; i < 4; ++i)                                 \
            _Pragma("unroll") for (int j = 0; j < 4; ++j)                             \
                acc[i + 4][j] = MF(falo[i + 4], fbhi[j], acc[i + 4][j]);              \
        PRIO0; BARF();                                                                \
        /* P5+P6: seg2 full (fahi still live in regs) */                              \
        _Pragma("unroll") for (int j = 0; j < 4; ++j)                                 \
            fblo[j] = *(const short8*)&sB[bRead + j * 512];                           \
        BARF(); PRIO1;                                                                \
        _Pragma("unroll") for (int i = 0; i < 8; ++i)                                 \
            _Pragma("unroll") for (int j = 0; j < 4; ++j)                             \
                acc[i][j] = MF(fahi[i], fblo[j], acc[i][j]);                          \
        PRIO0; W6STMT; BARF();                                                        \
    } while (0)

    // prologue: stage chunk 0 (Ahi,Bhi -> slot0; Alo,Blo -> slot1), retire hi pair
    gll16(Ahi + aoff0, &lds[0] + ldsAo);
    gll16(Ahi + aoff1, &lds[0] + ldsAo + 4096);
    gll16(Bhi + boff0, &lds[0] + ldsBo);
    gll16(Bhi + boff1, &lds[0] + ldsBo + 4096);
    gll16(Alo + aoff0, &lds[16384] + ldsAo);
    gll16(Alo + aoff1, &lds[16384] + ldsAo + 4096);
    gll16(Blo + boff0, &lds[16384] + ldsBo);
    gll16(Blo + boff1, &lds[16384] + ldsBo + 4096);
    WAITV(4);
    BARF();

    unsigned rg = 0;
    const int nK = K >> 5;  // 32-wide k-chunks (even: 16 or 32)
#pragma unroll 1
    for (int c = 0; c < nK - 1; ++c) {
        const int kn = (c + 1) << 5;
        CHUNK(rg, 1, kn, WAITV(4), WAITV(4));
        rg ^= 2;
    }
    // last chunk: no staging; retire remaining lo-pair loads before P3/P5 reads
    CHUNK(rg, 0, 0, WAITV(0), (void)0);
#undef CHUNK
#undef MF
#undef PRIO1
#undef PRIO0
#undef WAITV
#undef BARF

    // C/D layout: col = lane&15, row = (lane>>4)*4 + reg
    const int col0 = bn + wc * 64 + (lane & 15);
    const int row0 = bm + wr * 128 + ((lane >> 4) << 2);
#pragma unroll
    for (int i = 0; i < 8; ++i) {
#pragma unroll
        for (int j = 0; j < 4; ++j) {
            int col = col0 + j * 16;
            if (col >= Nstore) continue;
            float badd = bias ? bias[col] : 0.f;
            int rowb = row0 + i * 16;
#pragma unroll
            for (int k = 0; k < 4; ++k) {
                int row = rowb + k;
                if (row < M) C[(size_t)row * ldc + col] = acc[i][j][k] + badd;
            }
        }
    }
}

// ---------------- el / er from z (one wave per row) ----------------
__global__ __launch_bounds__(256) void eler_kernel(
    const float* __restrict__ z, const float* __restrict__ al, const float* __restrict__ ar,
    float* __restrict__ el, float* __restrict__ er, int M) {
    int row = blockIdx.x * 4 + (threadIdx.x >> 6);
    int lane = threadIdx.x & 63;
    if (row >= M) return;
    const float4* zr = (const float4*)(z + (size_t)row * 512 + lane * 8);
    float4 z0 = zr[0], z1 = zr[1];
    const float4* alp = (const float4*)(al + lane * 8);
    float4 a0 = alp[0], a1 = alp[1];
    float s = z0.x * a0.x + z0.y * a0.y + z0.z * a0.z + z0.w * a0.w
            + z1.x * a1.x + z1.y * a1.y + z1.z * a1.z + z1.w * a1.w;
    s += __shfl_xor(s, 8); s += __shfl_xor(s, 4); s += __shfl_xor(s, 2); s += __shfl_xor(s, 1);
    int h = lane >> 4;
    if ((lane & 15) == 0) el[(size_t)row * 4 + h] = s;
    if (er) {
        const float4* arp = (const float4*)(ar + lane * 8);
        float4 b0 = arp[0], b1 = arp[1];
        float t = z0.x * b0.x + z0.y * b0.y + z0.z * b0.z + z0.w * b0.w
                + z1.x * b1.x + z1.y * b1.y + z1.z * b1.z + z1.w * b1.w;
        t += __shfl_xor(t, 8); t += __shfl_xor(t, 4); t += __shfl_xor(t, 2); t += __shfl_xor(t, 1);
        if ((lane & 15) == 0) er[(size_t)row * 4 + h] = t;
    }
}

// ---------------- fold: v[k,h] = sum_d W[k, h*128+d] * ar[h,d] ----------------
__global__ void fold_kernel(const float* __restrict__ W, const float* __restrict__ ar,
                            float* __restrict__ v, int K) {
    int i = blockIdx.x * 256 + threadIdx.x;
    if (i >= K * 4) return;
    int k = i >> 2, h = i & 3;
    const float* wr = W + (size_t)k * 512 + h * 128;
    const float* a = ar + h * 128;
    float s = 0.f;
#pragma unroll 4
    for (int d = 0; d < 128; ++d) s += wr[d] * a[d];
    v[i] = s;
}

// ---------------- skinny: er[M,4] = h[M,K] @ v[K,4] ----------------
__global__ __launch_bounds__(256) void skinny_kernel(
    const float* __restrict__ h, const float* __restrict__ v,
    float* __restrict__ er, int M, int K) {
    __shared__ float vs[4096];
    for (int i = threadIdx.x; i < K * 4; i += 256) vs[i] = v[i];
    __syncthreads();
    int row = blockIdx.x * 4 + (threadIdx.x >> 6);
    int lane = threadIdx.x & 63;
    if (row >= M) return;
    const float* hr = h + (size_t)row * K;
    float a0 = 0, a1 = 0, a2 = 0, a3 = 0;
    for (int k = lane; k < K; k += 64) {
        float x = hr[k];
        float4 vv = *(const float4*)&vs[k * 4];
        a0 += x * vv.x; a1 += x * vv.y; a2 += x * vv.z; a3 += x * vv.w;
    }
#pragma unroll
    for (int off = 32; off; off >>= 1) {
        a0 += __shfl_xor(a0, off); a1 += __shfl_xor(a1, off);
        a2 += __shfl_xor(a2, off); a3 += __shfl_xor(a3, off);
    }
    if (lane == 0) *(float4*)&er[(size_t)row * 4] = make_float4(a0, a1, a2, a3);
}

// ---------------- fused softmax-stats + aggregation (+relu +decomp) ----------------
__global__ __launch_bounds__(256) void agg_fused(
    const int* __restrict__ rp1, const int* __restrict__ col1, const float* __restrict__ z1,
    const float* __restrict__ el1, const float* __restrict__ er1,
    const int* __restrict__ rp2, const int* __restrict__ col2, const float* __restrict__ z2,
    const float* __restrict__ el2, const float* __restrict__ er2,
    float* __restrict__ out, unsigned short* __restrict__ hi, unsigned short* __restrict__ lo,
    int N, int do_relu) {
    int j = blockIdx.x * 4 + (threadIdx.x >> 6);
    int lane = threadIdx.x & 63;
    if (j >= N) return;
    int h = lane >> 4;
    float4 acc0 = make_float4(0, 0, 0, 0), acc1 = make_float4(0, 0, 0, 0);

    // ---- type 1 ----
    {
        int e0 = rp1[j], e1 = rp1[j + 1];
        float erh = er1[(size_t)j * 4 + h];
        float m = -INFINITY, s = 0.f;
        for (int e = e0; e < e1; ++e) {
            float x = el1[(size_t)col1[e] * 4 + h] + erh;
            x = (x >= 0.f) ? x : 0.2f * x;
            float mn = fmaxf(m, x);
            s = s * expf(m - mn) + expf(x - mn);
            m = mn;
        }
        float inv = 1.0f / (s + 1e-9f);
        for (int e = e0; e < e1; ++e) {
            int src = col1[e];
            float x = el1[(size_t)src * 4 + h] + erh;
            x = (x >= 0.f) ? x : 0.2f * x;
            float wgt = expf(x - m) * inv;
            const float4* zr = (const float4*)(z1 + (size_t)src * 512 + lane * 8);
            float4 za = zr[0], zb = zr[1];
            acc0.x += wgt * za.x; acc0.y += wgt * za.y; acc0.z += wgt * za.z; acc0.w += wgt * za.w;
            acc1.x += wgt * zb.x; acc1.y += wgt * zb.y; acc1.z += wgt * zb.z; acc1.w += wgt * zb.w;
        }
    }
    // ---- type 2 (optional) ----
    if (rp2) {
        int e0 = rp2[j], e1 = rp2[j + 1];
        float erh = er2[(size_t)j * 4 + h];
        float m = -INFINITY, s = 0.f;
        for (int e = e0; e < e1; ++e) {
            float x = el2[(size_t)col2[e] * 4 + h] + erh;
            x = (x >= 0.f) ? x : 0.2f * x;
            float mn = fmaxf(m, x);
            s = s * expf(m - mn) + expf(x - mn);
            m = mn;
        }
        float inv = 1.0f / (s + 1e-9f);
        for (int e = e0; e < e1; ++e) {
            int src = col2[e];
            float x = el2[(size_t)src * 4 + h] + erh;
            x = (x >= 0.f) ? x : 0.2f * x;
            float wgt = expf(x - m) * inv;
            const float4* zr = (const float4*)(z2 + (size_t)src * 512 + lane * 8);
            float4 za = zr[0], zb = zr[1];
            acc0.x += wgt * za.x; acc0.y += wgt * za.y; acc0.z += wgt * za.z; acc0.w += wgt * za.w;
            acc1.x += wgt * zb.x; acc1.y += wgt * zb.y; acc1.z += wgt * zb.z; acc1.w += wgt * zb.w;
        }
    }
    if (do_relu) {
        acc0.x = fmaxf(acc0.x, 0.f); acc0.y = fmaxf(acc0.y, 0.f);
        acc0.z = fmaxf(acc0.z, 0.f); acc0.w = fmaxf(acc0.w, 0.f);
        acc1.x = fmaxf(acc1.x, 0.f); acc1.y = fmaxf(acc1.y, 0.f);
        acc1.z = fmaxf(acc1.z, 0.f); acc1.w = fmaxf(acc1.w, 0.f);
    }
    float* op = out + (size_t)j * 512 + lane * 8;
    *(float4*)op = acc0;
    *(float4*)(op + 4) = acc1;
    if (hi) {
        size_t base = (size_t)j * 512 + lane * 8;
        ushort4 h0, h1, l0, l1;
        h0.x = f2bf(acc0.x); h0.y = f2bf(acc0.y); h0.z = f2bf(acc0.z); h0.w = f2bf(acc0.w);
        h1.x = f2bf(acc1.x); h1.y = f2bf(acc1.y); h1.z = f2bf(acc1.z); h1.w = f2bf(acc1.w);
        l0.x = f2bf(acc0.x - bf2f(h0.x)); l0.y = f2bf(acc0.y - bf2f(h0.y));
        l0.z = f2bf(acc0.z - bf2f(h0.z)); l0.w = f2bf(acc0.w - bf2f(h0.w));
        l1.x = f2bf(acc1.x - bf2f(h1.x)); l1.y = f2bf(acc1.y - bf2f(h1.y));
        l1.z = f2bf(acc1.z - bf2f(h1.z)); l1.w = f2bf(acc1.w - bf2f(h1.w));
        *(ushort4*)(hi + base) = h0;
        *(ushort4*)(hi + base + 4) = h1;
        *(ushort4*)(lo + base) = l0;
        *(ushort4*)(lo + base + 4) = l1;
    }
}

// ---------------- launcher ----------------
extern "C" void kernel_launch(void* const* d_in, const int* in_sizes, int n_in,
                              void* d_out, int out_size, void* d_ws, size_t ws_size,
                              hipStream_t stream) {
    const float* x_paper = (const float*)d_in[0];
    const float* x_author = (const float*)d_in[1];
    const int* cites_src = (const int*)d_in[2];
    const int* cites_dst = (const int*)d_in[3];
    const int* writes_src = (const int*)d_in[4];
    const int* writes_dst = (const int*)d_in[5];
    const int* wb_src = (const int*)d_in[6];
    const int* wb_dst = (const int*)d_in[7];
    const float* W0 = (const float*)d_in[8];
    const float* al0 = (const float*)d_in[9];
    const float* ar0 = (const float*)d_in[10];
    const float* W1 = (const float*)d_in[11];
    const float* al1 = (const float*)d_in[12];
    const float* ar1 = (const float*)d_in[13];
    const float* W2 = (const float*)d_in[14];
    const float* al2 = (const float*)d_in[15];
    const float* ar2 = (const float*)d_in[16];
    const float* linW = (const float*)d_in[17];
    const float* linb = (const float*)d_in[18];
    float* out = (float*)d_out;

    // allow 128KB dynamic LDS for the ring GEMM (host-side, capture-safe)
    (void)hipFuncSetAttribute((const void*)gemm_6ph,
                              hipFuncAttributeMaxDynamicSharedMemorySize, 131072);

    char* p = (char*)d_ws;
    auto alloc = [&](size_t n) { char* r = p; p += (n + 255) & ~(size_t)255; return r; };

    float* hpA = (float*)alloc((size_t)NP * 512 * 4);
    float* hpB = (float*)alloc((size_t)NP * 512 * 4);
    float* haA = (float*)alloc((size_t)NA * 512 * 4);
    float* haB = (float*)alloc((size_t)NA * 512 * 4);
    float* zbuf = (float*)alloc((size_t)NP * 512 * 4);   // paper-source z
    float* elA = (float*)alloc((size_t)NP * 16);
    float* erA = (float*)alloc((size_t)NP * 16);
    float* elB = (float*)alloc((size_t)NP * 16);
    float* erB = (float*)alloc((size_t)NP * 16);
    float* vfold = (float*)alloc(4096 * 4);
    int* rp_c = (int*)alloc((NP + 1) * 4);
    int* col_c = (int*)alloc((size_t)EC * 4);
    int* rp_w = (int*)alloc((NP + 1) * 4);
    int* col_w = (int*)alloc((size_t)EW * 4);
    int* rp_b = (int*)alloc((NA + 1) * 4);
    int* col_b = (int*)alloc((size_t)EB * 4);
    int* cursor = (int*)alloc((NP + 1) * 4);
    int* counts = (int*)alloc((size_t)NP * 4);

    unsigned short* AhiP = (unsigned short*)alloc((size_t)MPAD_P * 1024 * 2);
    unsigned short* AloP = (unsigned short*)alloc((size_t)MPAD_P * 1024 * 2);
    unsigned short* AhiA = (unsigned short*)alloc((size_t)MPAD_A * 1024 * 2);
    unsigned short* AloA = (unsigned short*)alloc((size_t)MPAD_A * 1024 * 2);
    const int Ks[3] = {IN_F, HID, HID};
    unsigned short *bthi[3][3], *btlo[3][3];
    for (int l = 0; l < 3; ++l)
        for (int t = 0; t < 3; ++t) {
            bthi[l][t] = (unsigned short*)alloc((size_t)512 * Ks[l] * 2);
            btlo[l][t] = (unsigned short*)alloc((size_t)512 * Ks[l] * 2);
        }
    unsigned short* btLhi = (unsigned short*)alloc((size_t)256 * 512 * 2);
    unsigned short* btLlo = (unsigned short*)alloc((size_t)256 * 512 * 2);
    (void)ws_size;

    // ---- CSR build ----
    struct EdgeT { const int* src; const int* dst; int E; int n; int* rp; int* col; };
    EdgeT ets[3] = {
        {cites_src, cites_dst, EC, NP, rp_c, col_c},
        {writes_src, writes_dst, EW, NP, rp_w, col_w},
        {wb_src, wb_dst, EB, NA, rp_b, col_b},
    };
    for (int t = 0; t < 3; ++t) {
        hipMemsetAsync(counts, 0, (size_t)ets[t].n * 4, stream);
        hist_kernel<<<(ets[t].E + 255) / 256, 256, 0, stream>>>(ets[t].dst, ets[t].E, counts);
        exscan_kernel<<<1, 256, 0, stream>>>(counts, ets[t].rp, ets[t].n);
        hipMemcpyAsync(cursor, ets[t].rp, (size_t)ets[t].n * 4, hipMemcpyDeviceToDevice, stream);
        fill_kernel<<<(ets[t].E + 255) / 256, 256, 0, stream>>>(ets[t].src, ets[t].dst, ets[t].E, cursor, ets[t].col);
    }

    const float* Wl[3] = {W0, W1, W2};
    const float* alL[3] = {al0, al1, al2};
    const float* arL[3] = {ar0, ar1, ar2};

    // ---- weight transpose + hi/lo decomposition ----
    for (int l = 0; l < 3; ++l) {
        int K = Ks[l];
        for (int t = 0; t < 3; ++t)
            btprep_kernel<<<(512 * K + 255) / 256, 256, 0, stream>>>(
                Wl[l] + (size_t)t * K * 512, bthi[l][t], btlo[l][t], K, 512, 512);
    }
    btprep_kernel<<<(256 * 512 + 255) / 256, 256, 0, stream>>>(linW, btLhi, btLlo, 512, NCLS, 256);

    // ---- layer-0 input decomposition ----
    decomp4_kernel<<<((size_t)MPAD_P * 1024 / 4 + 255) / 256, 256, 0, stream>>>(
        (const float4*)x_paper, (ushort4*)AhiP, (ushort4*)AloP, NP, 1024, MPAD_P);
    decomp4_kernel<<<((size_t)MPAD_A * 1024 / 4 + 255) / 256, 256, 0, stream>>>(
        (const float4*)x_author, (ushort4*)AhiA, (ushort4*)AloA, NA, 1024, MPAD_A);

    auto gemm = [&](const unsigned short* Ah, const unsigned short* Al,
                    const unsigned short* Bh, const unsigned short* Bl,
                    const float* bias, float* C, int M, int Mpad, int K, int gx,
                    int Nstore, int ldc) {
        dim3 g(gx, Mpad / 256);
        gemm_6ph<<<g, 512, 131072, stream>>>(Ah, Al, Bh, Bl, bias, C, M, K, Nstore, ldc);
    };

    const float* hp = x_paper;
    const float* ha = x_author;
    for (int l = 0; l < 3; ++l) {
        int K = Ks[l];
        float* hp_n = (l & 1) ? hpB : hpA;
        float* ha_n = (l & 1) ? haB : haA;
        float* zbuf_w = ha_n;  // alias: dead before agg_author writes ha_n
        const float* W = Wl[l];
        const float* al = alL[l];
        const float* ar = arL[l];
        size_t wstride = (size_t)K * 512;
        int relu = (l < 2) ? 1 : 0;

        // t0 (cites, paper z) and t1 (writes, author z) GEMMs
        gemm(AhiP, AloP, bthi[l][0], btlo[l][0], nullptr, zbuf, NP, MPAD_P, K, 2, 512, 512);
        gemm(AhiA, AloA, bthi[l][1], btlo[l][1], nullptr, zbuf_w, NA, MPAD_A, K, 2, 512, 512);
        // attention logits
        eler_kernel<<<(NP + 3) / 4, 256, 0, stream>>>(zbuf, al, ar, elA, erA, NP);
        eler_kernel<<<(NA + 3) / 4, 256, 0, stream>>>(zbuf_w, al + 512, nullptr, elB, nullptr, NA);
        fold_kernel<<<(K * 4 + 255) / 256, 256, 0, stream>>>(W + wstride, ar + 512, vfold, K);
        skinny_kernel<<<(NP + 3) / 4, 256, 0, stream>>>(hp, vfold, erB, NP, K);
        // paper aggregation: cites + writes fused (+relu)
        agg_fused<<<(NP + 3) / 4, 256, 0, stream>>>(
            rp_c, col_c, zbuf, elA, erA,
            rp_w, col_w, zbuf_w, elB, erB,
            hp_n, nullptr, nullptr, NP, relu);
        // t2 (wb, paper z) GEMM — must read old AhiP before decomp overwrites
        gemm(AhiP, AloP, bthi[l][2], btlo[l][2], nullptr, zbuf, NP, MPAD_P, K, 2, 512, 512);
        // paper decomp for next layer / final linear
        decomp4_kernel<<<((size_t)MPAD_P * 512 / 4 + 255) / 256, 256, 0, stream>>>(
            (const float4*)hp_n, (ushort4*)AhiP, (ushort4*)AloP, NP, 512, MPAD_P);
        // author aggregation (wb) (+relu +fused decomp)
        eler_kernel<<<(NP + 3) / 4, 256, 0, stream>>>(zbuf, al + 1024, nullptr, elA, nullptr, NP);
        fold_kernel<<<(K * 4 + 255) / 256, 256, 0, stream>>>(W + 2 * wstride, ar + 1024, vfold, K);
        skinny_kernel<<<(NA + 3) / 4, 256, 0, stream>>>(ha, vfold, erA, NA, K);
        agg_fused<<<(NA + 3) / 4, 256, 0, stream>>>(
            rp_b, col_b, zbuf, elA, erA,
            nullptr, nullptr, nullptr, nullptr, nullptr,
            ha_n, (l < 2) ? AhiA : nullptr, (l < 2) ? AloA : nullptr, NA, relu);
        hp = hp_n;
        ha = ha_n;
    }
    // ---- final linear ----
    gemm(AhiP, AloP, btLhi, btLlo, linb, out, NP, MPAD_P, 512, 1, NCLS, NCLS);
}

// Round 5
// 3190.388 us; speedup vs baseline: 1.0584x; 1.0080x over previous
//
#include <hip/hip_runtime.h>
#include <cstddef>
#include <cstdint>

// ---------------- problem constants (match reference) ----------------
static constexpr int NP = 60000, NA = 30000;
static constexpr int EC = 300000, EW = 150000, EB = 150000;
static constexpr int IN_F = 1024, HID = 512, H = 4, D = 128, NCLS = 153;
static constexpr int MPAD_P = 60160;  // 235 * 256
static constexpr int MPAD_A = 30208;  // 118 * 256

typedef __attribute__((ext_vector_type(8))) short short8;
typedef __attribute__((ext_vector_type(4))) float float4v;

// ---------------- bf16 helpers (RNE) ----------------
__device__ __forceinline__ unsigned short f2bf(float f) {
    unsigned int u = __float_as_uint(f);
    unsigned int r = u + 0x7FFFu + ((u >> 16) & 1u);
    return (unsigned short)(r >> 16);
}
__device__ __forceinline__ float bf2f(unsigned short h) {
    return __uint_as_float(((unsigned int)h) << 16);
}

// async global->LDS, 16B per lane; lds base must be wave-uniform
__device__ __forceinline__ void gll16(const unsigned short* g, unsigned short* l) {
    __builtin_amdgcn_global_load_lds(
        (const __attribute__((address_space(1))) unsigned int*)g,
        (__attribute__((address_space(3))) unsigned int*)l, 16, 0, 0);
}

// ---------------- CSR build ----------------
__global__ void hist_kernel(const int* __restrict__ dst, int E, int* __restrict__ counts) {
    int e = blockIdx.x * 256 + threadIdx.x;
    if (e < E) atomicAdd(&counts[dst[e]], 1);
}

__global__ void exscan_kernel(const int* __restrict__ in, int* __restrict__ out, int n) {
    __shared__ int wsum[4];
    int t = threadIdx.x;
    int lane = t & 63, w = t >> 6;
    int carry = 0;
    const int CH = 256 * 8;
    for (int base = 0; base < n; base += CH) {
        int v[8], run[8];
        int i0 = base + t * 8;
        int tsum = 0;
#pragma unroll
        for (int j = 0; j < 8; ++j) {
            int i = i0 + j;
            v[j] = (i < n) ? in[i] : 0;
            tsum += v[j];
            run[j] = tsum;
        }
        int x = tsum;
#pragma unroll
        for (int off = 1; off < 64; off <<= 1) {
            int y = __shfl_up(x, off);
            if (lane >= off) x += y;
        }
        if (lane == 63) wsum[w] = x;
        __syncthreads();
        int wpre = 0;
        for (int ww = 0; ww < w; ++ww) wpre += wsum[ww];
        int chunktot = wsum[0] + wsum[1] + wsum[2] + wsum[3];
        int pre = carry + wpre + (x - tsum);
#pragma unroll
        for (int j = 0; j < 8; ++j) {
            int i = i0 + j;
            if (i < n) out[i] = pre + run[j] - v[j];
        }
        carry += chunktot;
        __syncthreads();
    }
    if (t == 0) out[n] = carry;
}

__global__ void fill_kernel(const int* __restrict__ src, const int* __restrict__ dst, int E,
                            int* __restrict__ cursor, int* __restrict__ col) {
    int e = blockIdx.x * 256 + threadIdx.x;
    if (e < E) {
        int pos = atomicAdd(&cursor[dst[e]], 1);
        col[pos] = src[e];
    }
}

// ---------------- split-bf16 prep ----------------
__global__ void decomp4_kernel(const float4* __restrict__ x, ushort4* __restrict__ hi,
                               ushort4* __restrict__ lo, int M, int K, int Mpad) {
    size_t i4 = (size_t)blockIdx.x * 256 + threadIdx.x;
    size_t tot = ((size_t)Mpad * K) >> 2;
    if (i4 >= tot) return;
    size_t row = (i4 * 4) / (size_t)K;
    float4 v = make_float4(0.f, 0.f, 0.f, 0.f);
    if (row < (size_t)M) v = x[i4];
    ushort4 h, l;
    h.x = f2bf(v.x); h.y = f2bf(v.y); h.z = f2bf(v.z); h.w = f2bf(v.w);
    l.x = f2bf(v.x - bf2f(h.x)); l.y = f2bf(v.y - bf2f(h.y));
    l.z = f2bf(v.z - bf2f(h.z)); l.w = f2bf(v.w - bf2f(h.w));
    hi[i4] = h; lo[i4] = l;
}

// B (K x N, ld=N) -> BT hi/lo (Npad x K), zero pad rows
__global__ void btprep_kernel(const float* __restrict__ W, unsigned short* __restrict__ hi,
                              unsigned short* __restrict__ lo, int K, int N, int Npad) {
    int i = blockIdx.x * 256 + threadIdx.x;
    if (i >= Npad * K) return;
    int n = i / K, k = i - n * K;
    float v = (n < N) ? W[(size_t)k * N + n] : 0.f;
    unsigned short h = f2bf(v);
    hi[i] = h;
    lo[i] = f2bf(v - bf2f(h));
}

// ---------------- MFMA split-bf16 GEMM, read-ahead 5-group pipeline ------------
// C = (Ahi+Alo)[MxK] @ (Bhi+Blo)^T. Per 32-k chunk, 3 MFMA segments:
//   seg0: Ahi*Bhi, seg1: Alo*Bhi, seg2: Ahi*Blo  (per-acc order preserved)
// READ-AHEAD: group g issues the ds_reads for group g+1's MFMA so the LDS port
// drains UNDER the matrix pipes (compiler emits counted lgkmcnt for the deps).
// Ordering discipline (rule #18 / m201): bare s_barrier (NOT a "memory"-clobber
// asm, which can force a conservative vmcnt(0) drain and nullify counted vmcnt),
// with __builtin_amdgcn_sched_barrier(0) bracketing each barrier and following
// each counted wait — compile-time pins only, no runtime waitcnt.
// Groups (per wave): G1 seg0-low(16 MFMA, issue faU), G2 seg0-up(16, issue flL),
// G3 seg1-low(16, issue flU), G4 seg1-up(16, issue fblo), G5 seg2(32, issue next
// chunk's faL/fbL). Stages: G1 Ahi', G2 Bhi', G3 Alo', G4 Blo' (2 gll16 each).
// vmcnt ledger (in-order retire, verified): steady W1=4 (retires Alo_c, guards
// flL/flU), W3=6 (retires Blo_c, guards fblo), W4=4 (retires Ahi'/Bhi', guards
// next faL/fbL). Last chunk: W1=2, W3=0, W4=none. Chunk entry/exit pending = 4.
// LDS swizzle (verified 0-conflict): 16B chunk' = chunk ^ ((row>>1)&3),
// pre-swizzled global source (write side) + swizzled ds_read addr (read side).
__global__ __launch_bounds__(512, 2) void gemm_ra(
    const unsigned short* __restrict__ Ahi, const unsigned short* __restrict__ Alo,
    const unsigned short* __restrict__ Bhi, const unsigned short* __restrict__ Blo,
    const float* __restrict__ bias, float* __restrict__ C,
    int M, int K, int Nstore, int ldc) {
    extern __shared__ unsigned short lds[];  // 4 * 16384 shorts = 128KB
    const int tid = threadIdx.x;
    const int lane = tid & 63;
    const int w = tid >> 6;           // 8 waves
    const int wr = w >> 2, wc = w & 3;
    const int bm = blockIdx.y * 256, bn = blockIdx.x * 256;

    // ---- staging source (pre-swizzled 16B chunk): row = w*16 + (lane>>2) (+128)
    const int st_row = w * 16 + (lane >> 2);
    const int st_sc = (((lane & 3) ^ ((lane >> 3) & 3)) << 3);  // shorts
    const size_t aoff0 = (size_t)(bm + st_row) * K + st_sc;
    const size_t aoff1 = aoff0 + (size_t)128 * K;
    const size_t boff0 = (size_t)(bn + st_row) * K + st_sc;
    const size_t boff1 = boff0 + (size_t)128 * K;
    const int ldsAo = w * 512;          // within-slot offsets (shorts)
    const int ldsBo = 8192 + w * 512;

    // ---- fragment read addressing (swizzled)
    const int arow = wr * 128 + (lane & 15);
    const int brow = wc * 64 + (lane & 15);
    const int rq = ((((lane >> 4) & 3) ^ ((lane >> 1) & 3)) << 3);
    const int aRead = arow * 32 + rq;
    const int bRead = 8192 + brow * 32 + rq;

    float4v acc[8][4];
    float4v zf = {0.f, 0.f, 0.f, 0.f};
#pragma unroll
    for (int i = 0; i < 8; ++i)
#pragma unroll
        for (int j = 0; j < 4; ++j) acc[i][j] = zf;

    short8 faL[4], fbL[4], faU[4], flL[4], flU[4], fblo[4], nxA[4], nxB[4];

#define SBAR() __builtin_amdgcn_sched_barrier(0)
#define WAITV(n)                                      \
    do {                                              \
        asm volatile("s_waitcnt vmcnt(" #n ")");      \
        SBAR();                                       \
    } while (0)
#define BAR()                                         \
    do {                                              \
        SBAR();                                       \
        __builtin_amdgcn_s_barrier();                 \
        SBAR();                                       \
    } while (0)
#define PRIO1 __builtin_amdgcn_s_setprio(1)
#define PRIO0 __builtin_amdgcn_s_setprio(0)
#define MF(a, b, c) __builtin_amdgcn_mfma_f32_16x16x32_bf16(a, b, c, 0, 0, 0)

// One 32-k chunk = 5 groups, read-ahead one group. W*STMT run before the group's
// closing barrier. DOSTAGE/LASTC are literal 0/1.
#define CHUNK(RG, DOSTAGE, KN, W1STMT, W3STMT, W4STMT, LASTC)                         \
    do {                                                                              \
        const unsigned short* sA = &lds[(RG) * 16384u];          /* hi pair slot */   \
        const unsigned short* sB = &lds[((RG) + 1u) * 16384u];   /* lo pair slot */   \
        unsigned short* dA = &lds[((RG) ^ 2u) * 16384u];                              \
        unsigned short* dB = &lds[(((RG) ^ 2u) + 1u) * 16384u];                       \
        /* G1: MFMA seg0-low (faL x fbL); issue faU; stage Ahi' */                    \
        _Pragma("unroll") for (int i = 0; i < 4; ++i)                                 \
            faU[i] = *(const short8*)&sA[aRead + (i + 4) * 512];                      \
        if (DOSTAGE) {                                                                \
            gll16(Ahi + aoff0 + (KN), dA + ldsAo);                                    \
            gll16(Ahi + aoff1 + (KN), dA + ldsAo + 4096);                             \
        }                                                                             \
        PRIO1;                                                                        \
        _Pragma("unroll") for (int i = 0; i < 4; ++i)                                 \
            _Pragma("unroll") for (int j = 0; j < 4; ++j)                             \
                acc[i][j] = MF(faL[i], fbL[j], acc[i][j]);                            \
        PRIO0; W1STMT; BAR();                                                         \
        /* G2: seg0-up (faU x fbL); issue flL; stage Bhi' */                          \
        _Pragma("unroll") for (int i = 0; i < 4; ++i)                                 \
            flL[i] = *(const short8*)&sB[aRead + i * 512];                            \
        if (DOSTAGE) {                                                                \
            gll16(Bhi + boff0 + (KN), dA + ldsBo);                                    \
            gll16(Bhi + boff1 + (KN), dA + ldsBo + 4096);                             \
        }                                                                             \
        PRIO1;                                                                        \
        _Pragma("unroll") for (int i = 0; i < 4; ++i)                                 \
            _Pragma("unroll") for (int j = 0; j < 4; ++j)                             \
                acc[i + 4][j] = MF(faU[i], fbL[j], acc[i + 4][j]);                    \
        PRIO0; BAR();                                                                 \
        /* G3: seg1-low (flL x fbL); issue flU; stage Alo' */                         \
        _Pragma("unroll") for (int i = 0; i < 4; ++i)                                 \
            flU[i] = *(const short8*)&sB[aRead + (i + 4) * 512];                      \
        if (DOSTAGE) {                                                                \
            gll16(Alo + aoff0 + (KN), dB + ldsAo);                                    \
            gll16(Alo + aoff1 + (KN), dB + ldsAo + 4096);                             \
        }                                                                             \
        PRIO1;                                                                        \
        _Pragma("unroll") for (int i = 0; i < 4; ++i)                                 \
            _Pragma("unroll") for (int j = 0; j < 4; ++j)                             \
                acc[i][j] = MF(flL[i], fbL[j], acc[i][j]);                            \
        PRIO0; W3STMT; BAR();                                                         \
        /* G4: seg1-up (flU x fbL); issue fblo; stage Blo' */                         \
        _Pragma("unroll") for (int j = 0; j < 4; ++j)                                 \
            fblo[j] = *(const short8*)&sB[bRead + j * 512];                           \
        if (DOSTAGE) {                                                                \
            gll16(Blo + boff0 + (KN), dB + ldsBo);                                    \
            gll16(Blo + boff1 + (KN), dB + ldsBo + 4096);                             \
        }                                                                             \
        PRIO1;                                                                        \
        _Pragma("unroll") for (int i = 0; i < 4; ++i)                                 \
            _Pragma("unroll") for (int j = 0; j < 4; ++j)                             \
                acc[i + 4][j] = MF(flU[i], fbL[j], acc[i + 4][j]);                    \
        PRIO0; W4STMT; BAR();                                                         \
        /* G5: seg2 (faL,faU x fblo); issue next chunk's faL/fbL from hi' slot */     \
        if (!(LASTC)) {                                                               \
            _Pragma("unroll") for (int i = 0; i < 4; ++i)                             \
                nxA[i] = *(const short8*)&dA[aRead + i * 512];                        \
            _Pragma("unroll") for (int j = 0; j < 4; ++j)                             \
                nxB[j] = *(const short8*)&dA[bRead + j * 512];                        \
        }                                                                             \
        PRIO1;                                                                        \
        _Pragma("unroll") for (int i = 0; i < 4; ++i)                                 \
            _Pragma("unroll") for (int j = 0; j < 4; ++j)                             \
                acc[i][j] = MF(faL[i], fblo[j], acc[i][j]);                           \
        _Pragma("unroll") for (int i = 0; i < 4; ++i)                                 \
            _Pragma("unroll") for (int j = 0; j < 4; ++j)                             \
                acc[i + 4][j] = MF(faU[i], fblo[j], acc[i + 4][j]);                   \
        PRIO0; BAR();                                                                 \
    } while (0)

    // prologue: stage chunk 0 (Ahi,Bhi -> slot0; Alo,Blo -> slot1); retire hi pair;
    // then issue chunk 0's G1 fragments (faL, fbL).
    gll16(Ahi + aoff0, &lds[0] + ldsAo);
    gll16(Ahi + aoff1, &lds[0] + ldsAo + 4096);
    gll16(Bhi + boff0, &lds[0] + ldsBo);
    gll16(Bhi + boff1, &lds[0] + ldsBo + 4096);
    gll16(Alo + aoff0, &lds[16384] + ldsAo);
    gll16(Alo + aoff1, &lds[16384] + ldsAo + 4096);
    gll16(Blo + boff0, &lds[16384] + ldsBo);
    gll16(Blo + boff1, &lds[16384] + ldsBo + 4096);
    WAITV(4);
    BAR();
#pragma unroll
    for (int i = 0; i < 4; ++i) faL[i] = *(const short8*)&lds[aRead + i * 512];
#pragma unroll
    for (int j = 0; j < 4; ++j) fbL[j] = *(const short8*)&lds[bRead + j * 512];

    unsigned rg = 0;
    const int nK = K >> 5;  // 32-wide k-chunks
#pragma unroll 1
    for (int c = 0; c < nK - 1; ++c) {
        const int kn = (c + 1) << 5;
        CHUNK(rg, 1, kn, WAITV(4), WAITV(6), WAITV(4), 0);
#pragma unroll
        for (int i = 0; i < 4; ++i) { faL[i] = nxA[i]; fbL[i] = nxB[i]; }
        rg ^= 2;
    }
    // last chunk: no staging; drain its own lo-pair before dependent reads
    CHUNK(rg, 0, 0, WAITV(2), WAITV(0), (void)0, 1);
#undef CHUNK
#undef MF
#undef PRIO1
#undef PRIO0
#undef BAR
#undef WAITV
#undef SBAR

    // C/D layout: col = lane&15, row = (lane>>4)*4 + reg
    const int col0 = bn + wc * 64 + (lane & 15);
    const int row0 = bm + wr * 128 + ((lane >> 4) << 2);
#pragma unroll
    for (int i = 0; i < 8; ++i) {
#pragma unroll
        for (int j = 0; j < 4; ++j) {
            int col = col0 + j * 16;
            if (col >= Nstore) continue;
            float badd = bias ? bias[col] : 0.f;
            int rowb = row0 + i * 16;
#pragma unroll
            for (int k = 0; k < 4; ++k) {
                int row = rowb + k;
                if (row < M) C[(size_t)row * ldc + col] = acc[i][j][k] + badd;
            }
        }
    }
}

// ---------------- el / er from z (one wave per row) ----------------
__global__ __launch_bounds__(256) void eler_kernel(
    const float* __restrict__ z, const float* __restrict__ al, const float* __restrict__ ar,
    float* __restrict__ el, float* __restrict__ er, int M) {
    int row = blockIdx.x * 4 + (threadIdx.x >> 6);
    int lane = threadIdx.x & 63;
    if (row >= M) return;
    const float4* zr = (const float4*)(z + (size_t)row * 512 + lane * 8);
    float4 z0 = zr[0], z1 = zr[1];
    const float4* alp = (const float4*)(al + lane * 8);
    float4 a0 = alp[0], a1 = alp[1];
    float s = z0.x * a0.x + z0.y * a0.y + z0.z * a0.z + z0.w * a0.w
            + z1.x * a1.x + z1.y * a1.y + z1.z * a1.z + z1.w * a1.w;
    s += __shfl_xor(s, 8); s += __shfl_xor(s, 4); s += __shfl_xor(s, 2); s += __shfl_xor(s, 1);
    int h = lane >> 4;
    if ((lane & 15) == 0) el[(size_t)row * 4 + h] = s;
    if (er) {
        const float4* arp = (const float4*)(ar + lane * 8);
        float4 b0 = arp[0], b1 = arp[1];
        float t = z0.x * b0.x + z0.y * b0.y + z0.z * b0.z + z0.w * b0.w
                + z1.x * b1.x + z1.y * b1.y + z1.z * b1.z + z1.w * b1.w;
        t += __shfl_xor(t, 8); t += __shfl_xor(t, 4); t += __shfl_xor(t, 2); t += __shfl_xor(t, 1);
        if ((lane & 15) == 0) er[(size_t)row * 4 + h] = t;
    }
}

// ---------------- fold: v[k,h] = sum_d W[k, h*128+d] * ar[h,d] ----------------
__global__ void fold_kernel(const float* __restrict__ W, const float* __restrict__ ar,
                            float* __restrict__ v, int K) {
    int i = blockIdx.x * 256 + threadIdx.x;
    if (i >= K * 4) return;
    int k = i >> 2, h = i & 3;
    const float* wr = W + (size_t)k * 512 + h * 128;
    const float* a = ar + h * 128;
    float s = 0.f;
#pragma unroll 4
    for (int d = 0; d < 128; ++d) s += wr[d] * a[d];
    v[i] = s;
}

// ---------------- skinny: er[M,4] = h[M,K] @ v[K,4] ----------------
__global__ __launch_bounds__(256) void skinny_kernel(
    const float* __restrict__ h, const float* __restrict__ v,
    float* __restrict__ er, int M, int K) {
    __shared__ float vs[4096];
    for (int i = threadIdx.x; i < K * 4; i += 256) vs[i] = v[i];
    __syncthreads();
    int row = blockIdx.x * 4 + (threadIdx.x >> 6);
    int lane = threadIdx.x & 63;
    if (row >= M) return;
    const float* hr = h + (size_t)row * K;
    float a0 = 0, a1 = 0, a2 = 0, a3 = 0;
    for (int k = lane; k < K; k += 64) {
        float x = hr[k];
        float4 vv = *(const float4*)&vs[k * 4];
        a0 += x * vv.x; a1 += x * vv.y; a2 += x * vv.z; a3 += x * vv.w;
    }
#pragma unroll
    for (int off = 32; off; off >>= 1) {
        a0 += __shfl_xor(a0, off); a1 += __shfl_xor(a1, off);
        a2 += __shfl_xor(a2, off); a3 += __shfl_xor(a3, off);
    }
    if (lane == 0) *(float4*)&er[(size_t)row * 4] = make_float4(a0, a1, a2, a3);
}

// ---------------- fused softmax-stats + aggregation (+relu +decomp) ----------------
__global__ __launch_bounds__(256) void agg_fused(
    const int* __restrict__ rp1, const int* __restrict__ col1, const float* __restrict__ z1,
    const float* __restrict__ el1, const float* __restrict__ er1,
    const int* __restrict__ rp2, const int* __restrict__ col2, const float* __restrict__ z2,
    const float* __restrict__ el2, const float* __restrict__ er2,
    float* __restrict__ out, unsigned short* __restrict__ hi, unsigned short* __restrict__ lo,
    int N, int do_relu) {
    int j = blockIdx.x * 4 + (threadIdx.x >> 6);
    int lane = threadIdx.x & 63;
    if (j >= N) return;
    int h = lane >> 4;
    float4 acc0 = make_float4(0, 0, 0, 0), acc1 = make_float4(0, 0, 0, 0);

    // ---- type 1 ----
    {
        int e0 = rp1[j], e1 = rp1[j + 1];
        float erh = er1[(size_t)j * 4 + h];
        float m = -INFINITY, s = 0.f;
        for (int e = e0; e < e1; ++e) {
            float x = el1[(size_t)col1[e] * 4 + h] + erh;
            x = (x >= 0.f) ? x : 0.2f * x;
            float mn = fmaxf(m, x);
            s = s * expf(m - mn) + expf(x - mn);
            m = mn;
        }
        float inv = 1.0f / (s + 1e-9f);
        for (int e = e0; e < e1; ++e) {
            int src = col1[e];
            float x = el1[(size_t)src * 4 + h] + erh;
            x = (x >= 0.f) ? x : 0.2f * x;
            float wgt = expf(x - m) * inv;
            const float4* zr = (const float4*)(z1 + (size_t)src * 512 + lane * 8);
            float4 za = zr[0], zb = zr[1];
            acc0.x += wgt * za.x; acc0.y += wgt * za.y; acc0.z += wgt * za.z; acc0.w += wgt * za.w;
            acc1.x += wgt * zb.x; acc1.y += wgt * zb.y; acc1.z += wgt * zb.z; acc1.w += wgt * zb.w;
        }
    }
    // ---- type 2 (optional) ----
    if (rp2) {
        int e0 = rp2[j], e1 = rp2[j + 1];
        float erh = er2[(size_t)j * 4 + h];
        float m = -INFINITY, s = 0.f;
        for (int e = e0; e < e1; ++e) {
            float x = el2[(size_t)col2[e] * 4 + h] + erh;
            x = (x >= 0.f) ? x : 0.2f * x;
            float mn = fmaxf(m, x);
            s = s * expf(m - mn) + expf(x - mn);
            m = mn;
        }
        float inv = 1.0f / (s + 1e-9f);
        for (int e = e0; e < e1; ++e) {
            int src = col2[e];
            float x = el2[(size_t)src * 4 + h] + erh;
            x = (x >= 0.f) ? x : 0.2f * x;
            float wgt = expf(x - m) * inv;
            const float4* zr = (const float4*)(z2 + (size_t)src * 512 + lane * 8);
            float4 za = zr[0], zb = zr[1];
            acc0.x += wgt * za.x; acc0.y += wgt * za.y; acc0.z += wgt * za.z; acc0.w += wgt * za.w;
            acc1.x += wgt * zb.x; acc1.y += wgt * zb.y; acc1.z += wgt * zb.z; acc1.w += wgt * zb.w;
        }
    }
    if (do_relu) {
        acc0.x = fmaxf(acc0.x, 0.f); acc0.y = fmaxf(acc0.y, 0.f);
        acc0.z = fmaxf(acc0.z, 0.f); acc0.w = fmaxf(acc0.w, 0.f);
        acc1.x = fmaxf(acc1.x, 0.f); acc1.y = fmaxf(acc1.y, 0.f);
        acc1.z = fmaxf(acc1.z, 0.f); acc1.w = fmaxf(acc1.w, 0.f);
    }
    float* op = out + (size_t)j * 512 + lane * 8;
    *(float4*)op = acc0;
    *(float4*)(op + 4) = acc1;
    if (hi) {
        size_t base = (size_t)j * 512 + lane * 8;
        ushort4 h0, h1, l0, l1;
        h0.x = f2bf(acc0.x); h0.y = f2bf(acc0.y); h0.z = f2bf(acc0.z); h0.w = f2bf(acc0.w);
        h1.x = f2bf(acc1.x); h1.y = f2bf(acc1.y); h1.z = f2bf(acc1.z); h1.w = f2bf(acc1.w);
        l0.x = f2bf(acc0.x - bf2f(h0.x)); l0.y = f2bf(acc0.y - bf2f(h0.y));
        l0.z = f2bf(acc0.z - bf2f(h0.z)); l0.w = f2bf(acc0.w - bf2f(h0.w));
        l1.x = f2bf(acc1.x - bf2f(h1.x)); l1.y = f2bf(acc1.y - bf2f(h1.y));
        l1.z = f2bf(acc1.z - bf2f(h1.z)); l1.w = f2bf(acc1.w - bf2f(h1.w));
        *(ushort4*)(hi + base) = h0;
        *(ushort4*)(hi + base + 4) = h1;
        *(ushort4*)(lo + base) = l0;
        *(ushort4*)(lo + base + 4) = l1;
    }
}

// ---------------- launcher ----------------
extern "C" void kernel_launch(void* const* d_in, const int* in_sizes, int n_in,
                              void* d_out, int out_size, void* d_ws, size_t ws_size,
                              hipStream_t stream) {
    const float* x_paper = (const float*)d_in[0];
    const float* x_author = (const float*)d_in[1];
    const int* cites_src = (const int*)d_in[2];
    const int* cites_dst = (const int*)d_in[3];
    const int* writes_src = (const int*)d_in[4];
    const int* writes_dst = (const int*)d_in[5];
    const int* wb_src = (const int*)d_in[6];
    const int* wb_dst = (const int*)d_in[7];
    const float* W0 = (const float*)d_in[8];
    const float* al0 = (const float*)d_in[9];
    const float* ar0 = (const float*)d_in[10];
    const float* W1 = (const float*)d_in[11];
    const float* al1 = (const float*)d_in[12];
    const float* ar1 = (const float*)d_in[13];
    const float* W2 = (const float*)d_in[14];
    const float* al2 = (const float*)d_in[15];
    const float* ar2 = (const float*)d_in[16];
    const float* linW = (const float*)d_in[17];
    const float* linb = (const float*)d_in[18];
    float* out = (float*)d_out;

    // allow 128KB dynamic LDS for the ring GEMM (host-side, capture-safe)
    (void)hipFuncSetAttribute((const void*)gemm_ra,
                              hipFuncAttributeMaxDynamicSharedMemorySize, 131072);

    char* p = (char*)d_ws;
    auto alloc = [&](size_t n) { char* r = p; p += (n + 255) & ~(size_t)255; return r; };

    float* hpA = (float*)alloc((size_t)NP * 512 * 4);
    float* hpB = (float*)alloc((size_t)NP * 512 * 4);
    float* haA = (float*)alloc((size_t)NA * 512 * 4);
    float* haB = (float*)alloc((size_t)NA * 512 * 4);
    float* zbuf = (float*)alloc((size_t)NP * 512 * 4);   // paper-source z
    float* elA = (float*)alloc((size_t)NP * 16);
    float* erA = (float*)alloc((size_t)NP * 16);
    float* elB = (float*)alloc((size_t)NP * 16);
    float* erB = (float*)alloc((size_t)NP * 16);
    float* vfold = (float*)alloc(4096 * 4);
    int* rp_c = (int*)alloc((NP + 1) * 4);
    int* col_c = (int*)alloc((size_t)EC * 4);
    int* rp_w = (int*)alloc((NP + 1) * 4);
    int* col_w = (int*)alloc((size_t)EW * 4);
    int* rp_b = (int*)alloc((NA + 1) * 4);
    int* col_b = (int*)alloc((size_t)EB * 4);
    int* cursor = (int*)alloc((NP + 1) * 4);
    int* counts = (int*)alloc((size_t)NP * 4);

    unsigned short* AhiP = (unsigned short*)alloc((size_t)MPAD_P * 1024 * 2);
    unsigned short* AloP = (unsigned short*)alloc((size_t)MPAD_P * 1024 * 2);
    unsigned short* AhiA = (unsigned short*)alloc((size_t)MPAD_A * 1024 * 2);
    unsigned short* AloA = (unsigned short*)alloc((size_t)MPAD_A * 1024 * 2);
    const int Ks[3] = {IN_F, HID, HID};
    unsigned short *bthi[3][3], *btlo[3][3];
    for (int l = 0; l < 3; ++l)
        for (int t = 0; t < 3; ++t) {
            bthi[l][t] = (unsigned short*)alloc((size_t)512 * Ks[l] * 2);
            btlo[l][t] = (unsigned short*)alloc((size_t)512 * Ks[l] * 2);
        }
    unsigned short* btLhi = (unsigned short*)alloc((size_t)256 * 512 * 2);
    unsigned short* btLlo = (unsigned short*)alloc((size_t)256 * 512 * 2);
    (void)ws_size;

    // ---- CSR build ----
    struct EdgeT { const int* src; const int* dst; int E; int n; int* rp; int* col; };
    EdgeT ets[3] = {
        {cites_src, cites_dst, EC, NP, rp_c, col_c},
        {writes_src, writes_dst, EW, NP, rp_w, col_w},
        {wb_src, wb_dst, EB, NA, rp_b, col_b},
    };
    for (int t = 0; t < 3; ++t) {
        hipMemsetAsync(counts, 0, (size_t)ets[t].n * 4, stream);
        hist_kernel<<<(ets[t].E + 255) / 256, 256, 0, stream>>>(ets[t].dst, ets[t].E, counts);
        exscan_kernel<<<1, 256, 0, stream>>>(counts, ets[t].rp, ets[t].n);
        hipMemcpyAsync(cursor, ets[t].rp, (size_t)ets[t].n * 4, hipMemcpyDeviceToDevice, stream);
        fill_kernel<<<(ets[t].E + 255) / 256, 256, 0, stream>>>(ets[t].src, ets[t].dst, ets[t].E, cursor, ets[t].col);
    }

    const float* Wl[3] = {W0, W1, W2};
    const float* alL[3] = {al0, al1, al2};
    const float* arL[3] = {ar0, ar1, ar2};

    // ---- weight transpose + hi/lo decomposition ----
    for (int l = 0; l < 3; ++l) {
        int K = Ks[l];
        for (int t = 0; t < 3; ++t)
            btprep_kernel<<<(512 * K + 255) / 256, 256, 0, stream>>>(
                Wl[l] + (size_t)t * K * 512, bthi[l][t], btlo[l][t], K, 512, 512);
    }
    btprep_kernel<<<(256 * 512 + 255) / 256, 256, 0, stream>>>(linW, btLhi, btLlo, 512, NCLS, 256);

    // ---- layer-0 input decomposition ----
    decomp4_kernel<<<((size_t)MPAD_P * 1024 / 4 + 255) / 256, 256, 0, stream>>>(
        (const float4*)x_paper, (ushort4*)AhiP, (ushort4*)AloP, NP, 1024, MPAD_P);
    decomp4_kernel<<<((size_t)MPAD_A * 1024 / 4 + 255) / 256, 256, 0, stream>>>(
        (const float4*)x_author, (ushort4*)AhiA, (ushort4*)AloA, NA, 1024, MPAD_A);

    auto gemm = [&](const unsigned short* Ah, const unsigned short* Al,
                    const unsigned short* Bh, const unsigned short* Bl,
                    const float* bias, float* C, int M, int Mpad, int K, int gx,
                    int Nstore, int ldc) {
        dim3 g(gx, Mpad / 256);
        gemm_ra<<<g, 512, 131072, stream>>>(Ah, Al, Bh, Bl, bias, C, M, K, Nstore, ldc);
    };

    const float* hp = x_paper;
    const float* ha = x_author;
    for (int l = 0; l < 3; ++l) {
        int K = Ks[l];
        float* hp_n = (l & 1) ? hpB : hpA;
        float* ha_n = (l & 1) ? haB : haA;
        float* zbuf_w = ha_n;  // alias: dead before agg_author writes ha_n
        const float* W = Wl[l];
        const float* al = alL[l];
        const float* ar = arL[l];
        size_t wstride = (size_t)K * 512;
        int relu = (l < 2) ? 1 : 0;

        // t0 (cites, paper z) and t1 (writes, author z) GEMMs
        gemm(AhiP, AloP, bthi[l][0], btlo[l][0], nullptr, zbuf, NP, MPAD_P, K, 2, 512, 512);
        gemm(AhiA, AloA, bthi[l][1], btlo[l][1], nullptr, zbuf_w, NA, MPAD_A, K, 2, 512, 512);
        // attention logits
        eler_kernel<<<(NP + 3) / 4, 256, 0, stream>>>(zbuf, al, ar, elA, erA, NP);
        eler_kernel<<<(NA + 3) / 4, 256, 0, stream>>>(zbuf_w, al + 512, nullptr, elB, nullptr, NA);
        fold_kernel<<<(K * 4 + 255) / 256, 256, 0, stream>>>(W + wstride, ar + 512, vfold, K);
        skinny_kernel<<<(NP + 3) / 4, 256, 0, stream>>>(hp, vfold, erB, NP, K);
        // paper aggregation: cites + writes fused (+relu)
        agg_fused<<<(NP + 3) / 4, 256, 0, stream>>>(
            rp_c, col_c, zbuf, elA, erA,
            rp_w, col_w, zbuf_w, elB, erB,
            hp_n, nullptr, nullptr, NP, relu);
        // t2 (wb, paper z) GEMM — must read old AhiP before decomp overwrites
        gemm(AhiP, AloP, bthi[l][2], btlo[l][2], nullptr, zbuf, NP, MPAD_P, K, 2, 512, 512);
        // paper decomp for next layer / final linear
        decomp4_kernel<<<((size_t)MPAD_P * 512 / 4 + 255) / 256, 256, 0, stream>>>(
            (const float4*)hp_n, (ushort4*)AhiP, (ushort4*)AloP, NP, 512, MPAD_P);
        // author aggregation (wb) (+relu +fused decomp)
        eler_kernel<<<(NP + 3) / 4, 256, 0, stream>>>(zbuf, al + 1024, nullptr, elA, nullptr, NP);
        fold_kernel<<<(K * 4 + 255) / 256, 256, 0, stream>>>(W + 2 * wstride, ar + 1024, vfold, K);
        skinny_kernel<<<(NA + 3) / 4, 256, 0, stream>>>(ha, vfold, erA, NA, K);
        agg_fused<<<(NA + 3) / 4, 256, 0, stream>>>(
            rp_b, col_b, zbuf, elA, erA,
            nullptr, nullptr, nullptr, nullptr, nullptr,
            ha_n, (l < 2) ? AhiA : nullptr, (l < 2) ? AloA : nullptr, NA, relu);
        hp = hp_n;
        ha = ha_n;
    }
    // ---- final linear ----
    gemm(AhiP, AloP, btLhi, btLlo, linb, out, NP, MPAD_P, 512, 1, NCLS, NCLS);
}